// Round 14
// baseline (105.885 us; speedup 1.0000x reference)
//
#include <hip/hip_runtime.h>

typedef float f32x2 __attribute__((ext_vector_type(2)));
typedef float f32x4 __attribute__((ext_vector_type(4)));
typedef float f32x16 __attribute__((ext_vector_type(16)));
typedef _Float16 half8 __attribute__((ext_vector_type(8)));
typedef _Float16 half4 __attribute__((ext_vector_type(4)));
typedef unsigned int u32;
typedef u32 u32x4 __attribute__((ext_vector_type(4)));

#define S_LEN 2048
#define NHEAD 16
#define HDIM 64
#define BATCH 2
#define WINDOW 512
#define M2_FIX 5.770780163555852f   /* 4.0 * log2(e) */
#define LOG2E 1.4426950408889634f

// Input-fragment layouts (A: [mt(256)][kt(16)][ch(2)][g(4)][c(16)][j(8)],
// W: same with nt(192)): lane = g*16+c -> every MFMA fragment load is
// base + lane*8 halfs = one coalesced 1KB wave transaction.
//   offA(m,k) = (m>>4)*16384 + (k>>6)*1024 + ((k>>5)&1)*512
//             + ((k>>3)&3)*128 + (m&15)*8 + (k&7)
// Output fragment-packed layouts (per bh, stride 131072 halfs):
//  Q/K tile t: [ch(4)][lane(64)][j(8)]  lane=((d>>3)&1)*32+(s&31), ch=d>>4, j=d&7
//  V   tile t: [sub(4)][lane(64)][j(8)] sub=(d>>5)*2+((s>>4)&1),
//                                       lane=((s>>3)&1)*32+(d&31), j=s&7

// ---------------- kernel 1: convert f32 -> f16, frag-packed ----------------
__global__ __launch_bounds__(256) void convert_kernel(
    const float4* __restrict__ hs, const float4* __restrict__ wq,
    const float4* __restrict__ wk, const float4* __restrict__ wv,
    _Float16* __restrict__ Af, _Float16* __restrict__ Wf) {
  int i = blockIdx.x * 256 + threadIdx.x;
  float4 v;
  _Float16* dst;
  size_t off;
  if (i < 1048576) {
    v = hs[i];
    const int m = i >> 8;
    const int k = (i * 4) & 1023;
    off = (size_t)(m >> 4) * 16384 + (k >> 6) * 1024 + ((k >> 5) & 1) * 512 +
          ((k >> 3) & 3) * 128 + (m & 15) * 8 + (k & 7);
    dst = Af;
  } else {
    int j = i - 1048576;
    int kind;
    if (j < 262144) { v = wq[j]; kind = 0; }
    else if (j < 524288) { v = wk[j - 262144]; kind = 1; j -= 262144; }
    else { v = wv[j - 524288]; kind = 2; j -= 524288; }
    const int n = (j >> 8) + (kind << 10);
    const int k = (j * 4) & 1023;
    off = (size_t)(n >> 4) * 16384 + (k >> 6) * 1024 + ((k >> 5) & 1) * 512 +
          ((k >> 3) & 3) * 128 + (n & 15) * 8 + (k & 7);
    dst = Wf;
  }
  half4 o;
  o[0] = (_Float16)v.x; o[1] = (_Float16)v.y;
  o[2] = (_Float16)v.z; o[3] = (_Float16)v.w;
  *(half4*)&dst[off] = o;
}

// ---------------- kernel 2: QKV GEMM, LDS-free main loop --------------------
// 4 waves x 64x64 wave-tiles (128x128 block tile). All fragments loaded
// directly from frag-packed global (coalesced, L2/L3-served), one-step
// register prefetch. No LDS, no barriers in the main loop.
__global__ __launch_bounds__(256) void qkv_gemm(
    const _Float16* __restrict__ Af, const _Float16* __restrict__ Wf,
    const float* __restrict__ bq, const float* __restrict__ bk,
    const float* __restrict__ bv,
    _Float16* __restrict__ Qf, _Float16* __restrict__ Kf, _Float16* __restrict__ Vf) {
  __shared__ _Float16 ob4[16384];       // 32KB, epilogue bounce only
  const int tid = threadIdx.x;
  const int wv = tid >> 6;
  const int lane = tid & 63;
  const int g = lane >> 4;
  const int c = lane & 15;
  // 2D XCD map (proven FETCH cut): xcd owns 8 m-panels x 12 n-panels.
  const int b = blockIdx.x;
  const int xcd = b & 7;
  const int s = b >> 3;                 // 0..95
  const int sub = s / 48;
  const int rem = s - sub * 48;
  const int m0 = (((xcd >> 1) << 3) + rem / 6) * 128;
  const int n0 = ((xcd & 1) * 12 + sub * 6 + rem % 6) * 128;
  const int wm = (wv & 1) * 64;
  const int wn = (wv >> 1) * 64;

  const _Float16* aP = Af + (size_t)((m0 + wm) >> 4) * 16384 + lane * 8;
  const _Float16* bP = Wf + (size_t)((n0 + wn) >> 4) * 16384 + lane * 8;

  f32x4 acc[4][4];
#pragma unroll
  for (int i = 0; i < 4; ++i)
#pragma unroll
    for (int j = 0; j < 4; ++j) acc[i][j] = (f32x4){0.f, 0.f, 0.f, 0.f};

#define LDT(dA, dB, t)                                                        \
  {                                                                           \
    _Pragma("unroll") for (int mf = 0; mf < 4; ++mf)                          \
        _Pragma("unroll") for (int ch = 0; ch < 2; ++ch) {                    \
      dA[mf][ch] = *(const half8*)&aP[mf * 16384 + (t) * 1024 + ch * 512];    \
      dB[mf][ch] = *(const half8*)&bP[mf * 16384 + (t) * 1024 + ch * 512];    \
    }                                                                         \
  }
#define CMP(sA, sB)                                                           \
  {                                                                           \
    _Pragma("unroll") for (int nf = 0; nf < 4; ++nf)                          \
        _Pragma("unroll") for (int mf = 0; mf < 4; ++mf) {                    \
      acc[mf][nf] = __builtin_amdgcn_mfma_f32_16x16x32_f16(                   \
          sA[mf][0], sB[nf][0], acc[mf][nf], 0, 0, 0);                        \
      acc[mf][nf] = __builtin_amdgcn_mfma_f32_16x16x32_f16(                   \
          sA[mf][1], sB[nf][1], acc[mf][nf], 0, 0, 0);                        \
    }                                                                         \
  }

  half8 afA[4][2], bfA[4][2], afB[4][2], bfB[4][2];
  LDT(afA, bfA, 0);
  for (int t = 0; t < 16; t += 2) {
    if (t + 1 < 16) LDT(afB, bfB, t + 1);
    CMP(afA, bfA);
    if (t + 2 < 16) LDT(afA, bfA, t + 2);
    CMP(afB, bfB);
  }

  // ---- epilogue: scatter into per-wave LDS tile (final frag layout), then
  //      contiguous 1KB global stores. Wave-private region. ----
  const int kind = n0 >> 10;                // 0=Q 1=K 2=V
  const int nb = (n0 + wn) & 1023;
  const int head = nb >> 6;
  const float* bias = kind == 0 ? bq : (kind == 1 ? bk : bv);
  _Float16* dst = kind == 0 ? Qf : (kind == 1 ? Kf : Vf);
  _Float16* ob = ob4 + wv * 4096;

  if (kind < 2) {
    const float scl = kind == 0 ? (0.125f * LOG2E) : 1.0f;
#pragma unroll
    for (int nf = 0; nf < 4; ++nf) {
      const int d = nf * 16 + c;
      const float bsv = bias[nb + d];
      const int base = nf * 512 + ((c >> 3) & 1) * 256 + (c & 7);
#pragma unroll
      for (int mf = 0; mf < 4; ++mf) {
#pragma unroll
        for (int r = 0; r < 4; ++r) {
          ob[(mf >> 1) * 2048 + base + (mf & 1) * 128 + g * 32 + r * 8] =
              (_Float16)((acc[mf][nf][r] + bsv) * scl);
        }
      }
    }
  } else {
#pragma unroll
    for (int nf = 0; nf < 4; ++nf) {
      const int d = nf * 16 + c;
      const float bsv = bias[nb + d];
#pragma unroll
      for (int mf = 0; mf < 4; ++mf) {
        half4 v4;
#pragma unroll
        for (int r = 0; r < 4; ++r) v4[r] = (_Float16)(acc[mf][nf][r] + bsv);
        *(half4*)&ob[(mf >> 1) * 2048 + ((nf >> 1) * 2 + (mf & 1)) * 512 +
                     ((g >> 1) * 32 + (nf & 1) * 16 + c) * 8 + (g & 1) * 4] = v4;
      }
    }
  }

  const int bI = (m0 + wm) >> 11;
  const size_t gbase = (size_t)(bI * NHEAD + head) * 131072 +
                       (size_t)(((m0 + wm) & 2047) >> 5) * 2048;
#pragma unroll
  for (int i = 0; i < 8; ++i) {
    half8 v = *(const half8*)&ob[i * 512 + lane * 8];
    *(half8*)&dst[gbase + i * 512 + lane * 8] = v;
  }
}

// ---------------- kernel 3: windowed flash attention (r13 verbatim) ---------
__global__ __launch_bounds__(256) void attn_kernel(
    const _Float16* __restrict__ Qf, const _Float16* __restrict__ Kf,
    const _Float16* __restrict__ Vf, const float* __restrict__ amask,
    float* __restrict__ out) {
  __shared__ _Float16 obuf[4][32][72];
  __shared__ float lbuf[4][32];
  const int tid = threadIdx.x;
  const int w = tid >> 6;
  const int lane = tid & 63;
  const int q31 = lane & 31;
  const int h = lane >> 5;
  const int bid = blockIdx.x;
  const int bh = bid & 31;
  const int idx = 63 - (bid >> 5);  // longest strips launch first
  const int i0 = idx * 32;
  const int bI = bh >> 4;
  const int head = bh & 15;

  const _Float16* Qh = Qf + (size_t)bh * 131072;
  const _Float16* Kh = Kf + (size_t)bh * 131072;
  const _Float16* Vh = Vf + (size_t)bh * 131072;
  const float* am = amask + (size_t)bI * S_LEN;

  const int q = i0 + q31;
  const int hiq = (q <= WINDOW) ? q : (q - WINDOW - 1);
  const int last = i0 + 31;
  const int himax = (last <= WINDOW) ? last
                    : ((i0 <= WINDOW) ? WINDOW : (last - WINDOW - 1));
  const int hiq_min = (last <= WINDOW) ? i0
                      : ((i0 > WINDOW) ? (i0 - WINDOW - 1) : 0);
  const int ntiles = (himax >> 5) + 1;
  const int nfull = (hiq_min + 1) >> 5;
  const int lim = hiq - 4 * h;

  half8 qf[4];
#pragma unroll
  for (int ch = 0; ch < 4; ++ch)
    qf[ch] = *(const half8*)&Qh[(size_t)idx * 2048 + ch * 512 + lane * 8];

  f32x16 zero16, m2init;
#pragma unroll
  for (int r = 0; r < 16; ++r) { zero16[r] = 0.f; m2init[r] = -M2_FIX; }
  f32x16 oacc0 = zero16, oacc1 = zero16;
  f32x2 lp[4];
#pragma unroll
  for (int r = 0; r < 4; ++r) lp[r] = (f32x2){0.f, 0.f};

  auto computeTile = [&](half8 k0, half8 k1, half8 k2, half8 k3,
                         half8 vf0, half8 vf1, half8 vf2, half8 vf3,
                         f32x4 am0, f32x4 am1, f32x4 am2, f32x4 am3, int t)
      __attribute__((always_inline)) {
    const int j0 = t * 32;
    f32x4 amv[4] = {am0, am1, am2, am3};

    __builtin_amdgcn_s_setprio(1);
    f32x16 st = __builtin_amdgcn_mfma_f32_32x32x16_f16(k0, qf[0], m2init, 0, 0, 0);
    st = __builtin_amdgcn_mfma_f32_32x32x16_f16(k1, qf[1], st, 0, 0, 0);
    st = __builtin_amdgcn_mfma_f32_32x32x16_f16(k2, qf[2], st, 0, 0, 0);
    st = __builtin_amdgcn_mfma_f32_32x32x16_f16(k3, qf[3], st, 0, 0, 0);
    __builtin_amdgcn_s_setprio(0);

    float p[16];
#pragma unroll
    for (int r = 0; r < 16; ++r)
      p[r] = __builtin_fmaf(amv[r >> 2][r & 3], LOG2E, st[r]);
    if (t >= nfull) {
      const int lm = lim - j0;
#pragma unroll
      for (int r = 0; r < 16; ++r) {
        const int off = (r & 3) + 8 * (r >> 2);
        p[r] = (off <= lm) ? p[r] : -3e38f;
      }
    }
#pragma unroll
    for (int r = 0; r < 16; ++r) p[r] = __builtin_amdgcn_exp2f(p[r]);
#pragma unroll
    for (int j = 0; j < 4; ++j) {
      lp[j] += (f32x2){p[2 * j], p[2 * j + 1]};
      lp[j] += (f32x2){p[8 + 2 * j], p[9 + 2 * j]};
    }

    u32 pk[8];
#pragma unroll
    for (int r = 0; r < 8; ++r) {
      auto c2 = __builtin_amdgcn_cvt_pkrtz(p[2 * r], p[2 * r + 1]);
      pk[r] = __builtin_bit_cast(u32, c2);
    }
    u32 a0 = pk[0], b0 = pk[2];
    u32 a1 = pk[1], b1 = pk[3];
    u32 a2 = pk[4], b2 = pk[6];
    u32 a3 = pk[5], b3 = pk[7];
    asm("v_permlane32_swap_b32 %0, %1" : "+v"(a0), "+v"(b0));
    asm("v_permlane32_swap_b32 %0, %1" : "+v"(a1), "+v"(b1));
    asm("v_permlane32_swap_b32 %0, %1" : "+v"(a2), "+v"(b2));
    asm("v_permlane32_swap_b32 %0, %1" : "+v"(a3), "+v"(b3));
    const half8 pf0 = __builtin_bit_cast(half8, (u32x4){a0, a1, b0, b1});
    const half8 pf1 = __builtin_bit_cast(half8, (u32x4){a2, a3, b2, b3});

    __builtin_amdgcn_s_setprio(1);
    oacc0 = __builtin_amdgcn_mfma_f32_32x32x16_f16(vf0, pf0, oacc0, 0, 0, 0);
    oacc0 = __builtin_amdgcn_mfma_f32_32x32x16_f16(vf1, pf1, oacc0, 0, 0, 0);
    oacc1 = __builtin_amdgcn_mfma_f32_32x32x16_f16(vf2, pf0, oacc1, 0, 0, 0);
    oacc1 = __builtin_amdgcn_mfma_f32_32x32x16_f16(vf3, pf1, oacc1, 0, 0, 0);
    __builtin_amdgcn_s_setprio(0);
  };

#define LOADALL(k0, k1, k2, k3, v0, v1, v2, v3, a0_, a1_, a2_, a3_, tt)  \
  {                                                                      \
    const _Float16* kt = Kh + (size_t)(tt) * 2048 + lane * 8;            \
    const _Float16* vt = Vh + (size_t)(tt) * 2048 + lane * 8;            \
    const float* at = am + (tt) * 32 + 4 * h;                            \
    k0 = *(const half8*)&kt[0];                                          \
    k1 = *(const half8*)&kt[512];                                        \
    k2 = *(const half8*)&kt[1024];                                       \
    k3 = *(const half8*)&kt[1536];                                       \
    v0 = *(const half8*)&vt[0];                                          \
    v1 = *(const half8*)&vt[512];                                        \
    v2 = *(const half8*)&vt[1024];                                       \
    v3 = *(const half8*)&vt[1536];                                       \
    a0_ = *(const f32x4*)&at[0];                                         \
    a1_ = *(const f32x4*)&at[8];                                         \
    a2_ = *(const f32x4*)&at[16];                                        \
    a3_ = *(const f32x4*)&at[24];                                        \
  }

  int t = w;
  if (t < ntiles) {
    half8 k0, k1, k2, k3, v0, v1, v2, v3;
    f32x4 a0, a1, a2, a3;
    LOADALL(k0, k1, k2, k3, v0, v1, v2, v3, a0, a1, a2, a3, t);
    int tn = t + 4;
    while (tn < ntiles) {
      half8 n0, n1, n2, n3, u0, u1, u2, u3;
      f32x4 e0, e1, e2, e3;
      LOADALL(n0, n1, n2, n3, u0, u1, u2, u3, e0, e1, e2, e3, tn);
      computeTile(k0, k1, k2, k3, v0, v1, v2, v3, a0, a1, a2, a3, t);
      k0 = n0; k1 = n1; k2 = n2; k3 = n3;
      v0 = u0; v1 = u1; v2 = u2; v3 = u3;
      a0 = e0; a1 = e1; a2 = e2; a3 = e3;
      t = tn;
      tn += 4;
    }
    computeTile(k0, k1, k2, k3, v0, v1, v2, v3, a0, a1, a2, a3, t);
  }

  f32x2 s2 = (lp[0] + lp[1]) + (lp[2] + lp[3]);
  float lw = s2[0] + s2[1];
  lw += __shfl_xor(lw, 32);
  if (h == 0) lbuf[w][q31] = lw;
#pragma unroll
  for (int j = 0; j < 4; ++j) {
    half4 h0, h1;
#pragma unroll
    for (int e = 0; e < 4; ++e) {
      h0[e] = (_Float16)oacc0[4 * j + e];
      h1[e] = (_Float16)oacc1[4 * j + e];
    }
    *(half4*)&obuf[w][q31][4 * h + 8 * j]      = h0;
    *(half4*)&obuf[w][q31][32 + 4 * h + 8 * j] = h1;
  }
  __syncthreads();

  const int mq = tid >> 3;
  const int md = (tid & 7) * 8;
  const float lt = (lbuf[0][mq] + lbuf[1][mq]) + (lbuf[2][mq] + lbuf[3][mq]);
  float s[8];
  half8 p0 = *(const half8*)&obuf[0][mq][md];
#pragma unroll
  for (int e = 0; e < 8; ++e) s[e] = (float)p0[e];
#pragma unroll
  for (int w4 = 1; w4 < 4; ++w4) {
    half8 pw = *(const half8*)&obuf[w4][mq][md];
#pragma unroll
    for (int e = 0; e < 8; ++e) s[e] += (float)pw[e];
  }
  const float inv = 1.0f / lt;
  float4 s0, s1;
  s0.x = s[0] * inv; s0.y = s[1] * inv; s0.z = s[2] * inv; s0.w = s[3] * inv;
  s1.x = s[4] * inv; s1.y = s[5] * inv; s1.z = s[6] * inv; s1.w = s[7] * inv;
  float* op = out + ((size_t)(bI * S_LEN + i0 + mq)) * 1024 + head * 64 + md;
  *(float4*)op = s0;
  *(float4*)(op + 4) = s1;
}

// ---------------- launch --------------------------------------------------
extern "C" void kernel_launch(void* const* d_in, const int* in_sizes, int n_in,
                              void* d_out, int out_size, void* d_ws, size_t ws_size,
                              hipStream_t stream) {
  const float* hs = (const float*)d_in[0];
  const float* am = (const float*)d_in[1];
  const float* Wq = (const float*)d_in[2];
  const float* bq = (const float*)d_in[3];
  const float* Wk = (const float*)d_in[4];
  const float* bk = (const float*)d_in[5];
  const float* Wv = (const float*)d_in[6];
  const float* bv = (const float*)d_in[7];
  float* out = (float*)d_out;

  char* ws = (char*)d_ws;
  _Float16* Af  = (_Float16*)(ws);                       // 8 MiB frag-packed A
  _Float16* Wfb = (_Float16*)(ws + 8388608);             // 6 MiB frag-packed W
  _Float16* Qf  = (_Float16*)(ws + 14680064);
  _Float16* Kf  = (_Float16*)(ws + 23068672);
  _Float16* Vf  = (_Float16*)(ws + 31457280);

  convert_kernel<<<7168, 256, 0, stream>>>(
      (const float4*)hs, (const float4*)Wq, (const float4*)Wk, (const float4*)Wv, Af, Wfb);
  qkv_gemm<<<768, 256, 0, stream>>>(Af, Wfb, bq, bk, bv, Qf, Kf, Vf);
  attn_kernel<<<2048, 256, 0, stream>>>(Qf, Kf, Vf, am, out);
}

// Round 15
// 86.719 us; speedup vs baseline: 1.2210x; 1.2210x over previous
//
#include <hip/hip_runtime.h>

typedef float f32x2 __attribute__((ext_vector_type(2)));
typedef float f32x4 __attribute__((ext_vector_type(4)));
typedef float f32x16 __attribute__((ext_vector_type(16)));
typedef _Float16 half8 __attribute__((ext_vector_type(8)));
typedef _Float16 half4 __attribute__((ext_vector_type(4)));
typedef unsigned int u32;
typedef u32 u32x4 __attribute__((ext_vector_type(4)));

#define S_LEN 2048
#define NHEAD 16
#define HDIM 64
#define BATCH 2
#define WINDOW 512
#define M2_FIX 5.770780163555852f   /* 4.0 * log2(e) */
#define LOG2E 1.4426950408889634f

#define GLDS16(gp, lp) __builtin_amdgcn_global_load_lds( \
    (const __attribute__((address_space(1))) void*)(gp), \
    (__attribute__((address_space(3))) void*)(lp), 16, 0, 0)

// Fragment-packed layouts (per bh = b*16+head, stride 131072 halfs):
//  Q/K tile t: [ch(4)][lane(64)][j(8)]  lane=((d>>3)&1)*32+(s&31), ch=d>>4, j=d&7
//  V   tile t: [sub(4)][lane(64)][j(8)] sub=(d>>5)*2+((s>>4)&1),
//                                       lane=((s>>3)&1)*32+(d&31), j=s&7

// ---------------- kernel 1: convert hs + W(q,k,v) f32 -> f16 (r11) ----------
__global__ __launch_bounds__(256) void convert_kernel(
    const float4* __restrict__ hs, const float4* __restrict__ wq,
    const float4* __restrict__ wk, const float4* __restrict__ wv,
    _Float16* __restrict__ hsb, _Float16* __restrict__ wb) {
  int i = blockIdx.x * 256 + threadIdx.x;
  float4 v;
  _Float16* dst;
  if (i < 1048576) {
    v = hs[i];
    dst = hsb + (size_t)i * 4;
  } else {
    int j = i - 1048576;
    if (j < 262144) v = wq[j];
    else if (j < 524288) v = wk[j - 262144];
    else v = wv[j - 524288];
    dst = wb + (size_t)j * 4;
  }
  half4 o;
  o[0] = (_Float16)v.x; o[1] = (_Float16)v.y;
  o[2] = (_Float16)v.z; o[3] = (_Float16)v.w;
  *(half4*)dst = o;
}

// ---------------- kernel 2: QKV GEMM (r11 verbatim: BK=64, dbuf, 2D XCD) ----
__global__ __launch_bounds__(256) void qkv_gemm(
    const _Float16* __restrict__ A, const _Float16* __restrict__ W,
    const float* __restrict__ bq, const float* __restrict__ bk,
    const float* __restrict__ bv,
    _Float16* __restrict__ Qf, _Float16* __restrict__ Kf, _Float16* __restrict__ Vf) {
  __shared__ _Float16 sbuf[2][16384];
  const int tid = threadIdx.x;
  const int wv = tid >> 6;
  const int lane = tid & 63;
  const int g = lane >> 4;
  const int c = lane & 15;
  const int b = blockIdx.x;
  const int xcd = b & 7;
  const int s = b >> 3;
  const int sub = s / 48;
  const int rem = s - sub * 48;
  const int m0 = (((xcd >> 1) << 3) + rem / 6) * 128;
  const int n0 = ((xcd & 1) * 12 + sub * 6 + rem % 6) * 128;
  const int wm = (wv & 1) * 64;
  const int wn = (wv >> 1) * 64;

  const int srow8 = lane >> 3;
  const int sslot = lane & 7;
  const int lsl = sslot ^ srow8;
  const int rA = wv * 32 + srow8;
  const _Float16* aS = A + (size_t)(m0 + rA) * 1024 + lsl * 8;
  const _Float16* bS = W + (size_t)(n0 + rA) * 1024 + lsl * 8;
  const int rcolA0 = wv * 32 * 64;

  f32x4 acc[4][4];
#pragma unroll
  for (int i = 0; i < 4; ++i)
#pragma unroll
    for (int j = 0; j < 4; ++j) acc[i][j] = (f32x4){0.f, 0.f, 0.f, 0.f};

  auto STAGE = [&](int bf_, int k0) __attribute__((always_inline)) {
    char* aD = (char*)&sbuf[bf_][rcolA0];
    char* bD = (char*)&sbuf[bf_][8192 + rcolA0];
#pragma unroll
    for (int grp = 0; grp < 4; ++grp) {
      GLDS16(aS + grp * 8192 + k0, aD + grp * 1024);
      GLDS16(bS + grp * 8192 + k0, bD + grp * 1024);
    }
  };

  STAGE(0, 0);
  __syncthreads();
  int cur = 0;

  for (int t = 0; t < 16; ++t) {
    if (t < 15) STAGE(cur ^ 1, (t + 1) * 64);
    const _Float16* Asb = &sbuf[cur][0];
    const _Float16* Bsb = &sbuf[cur][8192];
    half8 af[4][2];
#pragma unroll
    for (int mf = 0; mf < 4; ++mf) {
      const int row = wm + mf * 16 + c;
#pragma unroll
      for (int ch = 0; ch < 2; ++ch)
        af[mf][ch] = *(const half8*)&Asb[row * 64 + ((ch * 4 + g) ^ (c & 7)) * 8];
    }
#pragma unroll
    for (int nf = 0; nf < 4; ++nf) {
      const int row = wn + nf * 16 + c;
      half8 bf0 = *(const half8*)&Bsb[row * 64 + ((g) ^ (c & 7)) * 8];
      half8 bf1 = *(const half8*)&Bsb[row * 64 + ((4 + g) ^ (c & 7)) * 8];
#pragma unroll
      for (int mf = 0; mf < 4; ++mf) {
        acc[mf][nf] = __builtin_amdgcn_mfma_f32_16x16x32_f16(af[mf][0], bf0, acc[mf][nf], 0, 0, 0);
        acc[mf][nf] = __builtin_amdgcn_mfma_f32_16x16x32_f16(af[mf][1], bf1, acc[mf][nf], 0, 0, 0);
      }
    }
    __syncthreads();
    cur ^= 1;
  }

  const int kind = n0 >> 10;
  const int nb = (n0 + wn) & 1023;
  const int head = nb >> 6;
  const float* bias = kind == 0 ? bq : (kind == 1 ? bk : bv);
  _Float16* dst = kind == 0 ? Qf : (kind == 1 ? Kf : Vf);
  _Float16* ob = &sbuf[0][wv * 4096];

  if (kind < 2) {
    const float scl = kind == 0 ? (0.125f * LOG2E) : 1.0f;
#pragma unroll
    for (int nf = 0; nf < 4; ++nf) {
      const int d = nf * 16 + c;
      const float bsv = bias[nb + d];
      const int base = nf * 512 + ((c >> 3) & 1) * 256 + (c & 7);
#pragma unroll
      for (int mf = 0; mf < 4; ++mf) {
#pragma unroll
        for (int r = 0; r < 4; ++r) {
          ob[(mf >> 1) * 2048 + base + (mf & 1) * 128 + g * 32 + r * 8] =
              (_Float16)((acc[mf][nf][r] + bsv) * scl);
        }
      }
    }
  } else {
#pragma unroll
    for (int nf = 0; nf < 4; ++nf) {
      const int d = nf * 16 + c;
      const float bsv = bias[nb + d];
#pragma unroll
      for (int mf = 0; mf < 4; ++mf) {
        half4 v4;
#pragma unroll
        for (int r = 0; r < 4; ++r) v4[r] = (_Float16)(acc[mf][nf][r] + bsv);
        *(half4*)&ob[(mf >> 1) * 2048 + ((nf >> 1) * 2 + (mf & 1)) * 512 +
                     ((g >> 1) * 32 + (nf & 1) * 16 + c) * 8 + (g & 1) * 4] = v4;
      }
    }
  }

  const int bI = (m0 + wm) >> 11;
  const size_t gbase = (size_t)(bI * NHEAD + head) * 131072 +
                       (size_t)(((m0 + wm) & 2047) >> 5) * 2048;
#pragma unroll
  for (int i = 0; i < 8; ++i) {
    half8 v = *(const half8*)&ob[i * 512 + lane * 8];
    *(half8*)&dst[gbase + i * 512 + lane * 8] = v;
  }
}

// ---------------- kernel 3: windowed flash attention, strip-PAIR blocks -----
// Block = (bh, strips {63-2p, 62-2p}): K/V/am tiles loaded ONCE feed BOTH
// strips (2x ILP per chain, half the loads). 4 waves k-split; frag-packed.
__global__ __launch_bounds__(256) void attn_kernel(
    const _Float16* __restrict__ Qf, const _Float16* __restrict__ Kf,
    const _Float16* __restrict__ Vf, const float* __restrict__ amask,
    float* __restrict__ out) {
  __shared__ _Float16 obuf[4][32][72];
  __shared__ float lbuf[4][32];
  const int tid = threadIdx.x;
  const int w = tid >> 6;
  const int lane = tid & 63;
  const int q31 = lane & 31;
  const int h = lane >> 5;
  const int bid = blockIdx.x;
  const int bh = bid & 31;
  const int pp = bid >> 5;              // 0..31, longest pairs first
  const int idxA = 63 - 2 * pp;
  const int idxB = 62 - 2 * pp;
  const int bI = bh >> 4;
  const int head = bh & 15;

  const _Float16* Qh = Qf + (size_t)bh * 131072;
  const _Float16* Kh = Kf + (size_t)bh * 131072;
  const _Float16* Vh = Vf + (size_t)bh * 131072;
  const float* am = amask + (size_t)bI * S_LEN;

  // per-strip window params
  auto stripParams = [&](int idx, int& nt, int& nfull, int& lim)
      __attribute__((always_inline)) {
    const int i0 = idx * 32;
    const int q = i0 + q31;
    const int hiq = (q <= WINDOW) ? q : (q - WINDOW - 1);
    const int last = i0 + 31;
    const int himax = (last <= WINDOW) ? last
                      : ((i0 <= WINDOW) ? WINDOW : (last - WINDOW - 1));
    const int hiq_min = (last <= WINDOW) ? i0
                        : ((i0 > WINDOW) ? (i0 - WINDOW - 1) : 0);
    nt = (himax >> 5) + 1;
    nfull = (hiq_min + 1) >> 5;
    lim = hiq - 4 * h;
  };
  int ntA, nfullA, limA, ntB, nfullB, limB;
  stripParams(idxA, ntA, nfullA, limA);
  stripParams(idxB, ntB, nfullB, limB);
  const int tmax = ntA > ntB ? ntA : ntB;   // straddle pair {17,16}: ntB>ntA

  half8 qfA[4], qfB[4];
#pragma unroll
  for (int ch = 0; ch < 4; ++ch) {
    qfA[ch] = *(const half8*)&Qh[(size_t)idxA * 2048 + ch * 512 + lane * 8];
    qfB[ch] = *(const half8*)&Qh[(size_t)idxB * 2048 + ch * 512 + lane * 8];
  }

  f32x16 m2init;
#pragma unroll
  for (int r = 0; r < 16; ++r) m2init[r] = -M2_FIX;
  f32x16 oA0 = {}, oA1 = {}, oB0 = {}, oB1 = {};
  f32x2 lpA[4] = {}, lpB[4] = {};

  auto doStrip = [&](f32x16& o0, f32x16& o1, f32x2* lp, const half8* qf,
                     int lim, int nfull, int t,
                     half8 k0, half8 k1, half8 k2, half8 k3,
                     half8 v0, half8 v1, half8 v2, half8 v3,
                     const f32x4* amv) __attribute__((always_inline)) {
    const int j0 = t * 32;
    __builtin_amdgcn_s_setprio(1);
    f32x16 st = __builtin_amdgcn_mfma_f32_32x32x16_f16(k0, qf[0], m2init, 0, 0, 0);
    st = __builtin_amdgcn_mfma_f32_32x32x16_f16(k1, qf[1], st, 0, 0, 0);
    st = __builtin_amdgcn_mfma_f32_32x32x16_f16(k2, qf[2], st, 0, 0, 0);
    st = __builtin_amdgcn_mfma_f32_32x32x16_f16(k3, qf[3], st, 0, 0, 0);
    __builtin_amdgcn_s_setprio(0);

    float p[16];
#pragma unroll
    for (int r = 0; r < 16; ++r)
      p[r] = __builtin_fmaf(amv[r >> 2][r & 3], LOG2E, st[r]);
    if (t >= nfull) {                  // wave-uniform: diagonal/straddle only
      const int lm = lim - j0;
#pragma unroll
      for (int r = 0; r < 16; ++r) {
        const int off = (r & 3) + 8 * (r >> 2);
        p[r] = (off <= lm) ? p[r] : -3e38f;
      }
    }
#pragma unroll
    for (int r = 0; r < 16; ++r) p[r] = __builtin_amdgcn_exp2f(p[r]);
#pragma unroll
    for (int j = 0; j < 4; ++j) {
      lp[j] += (f32x2){p[2 * j], p[2 * j + 1]};
      lp[j] += (f32x2){p[8 + 2 * j], p[9 + 2 * j]};
    }

    u32 pk[8];
#pragma unroll
    for (int r = 0; r < 8; ++r) {
      auto c2 = __builtin_amdgcn_cvt_pkrtz(p[2 * r], p[2 * r + 1]);
      pk[r] = __builtin_bit_cast(u32, c2);
    }
    u32 a0 = pk[0], b0 = pk[2];
    u32 a1 = pk[1], b1 = pk[3];
    u32 a2 = pk[4], b2 = pk[6];
    u32 a3 = pk[5], b3 = pk[7];
    asm("v_permlane32_swap_b32 %0, %1" : "+v"(a0), "+v"(b0));
    asm("v_permlane32_swap_b32 %0, %1" : "+v"(a1), "+v"(b1));
    asm("v_permlane32_swap_b32 %0, %1" : "+v"(a2), "+v"(b2));
    asm("v_permlane32_swap_b32 %0, %1" : "+v"(a3), "+v"(b3));
    const half8 pf0 = __builtin_bit_cast(half8, (u32x4){a0, a1, b0, b1});
    const half8 pf1 = __builtin_bit_cast(half8, (u32x4){a2, a3, b2, b3});

    __builtin_amdgcn_s_setprio(1);
    o0 = __builtin_amdgcn_mfma_f32_32x32x16_f16(v0, pf0, o0, 0, 0, 0);
    o0 = __builtin_amdgcn_mfma_f32_32x32x16_f16(v1, pf1, o0, 0, 0, 0);
    o1 = __builtin_amdgcn_mfma_f32_32x32x16_f16(v2, pf0, o1, 0, 0, 0);
    o1 = __builtin_amdgcn_mfma_f32_32x32x16_f16(v3, pf1, o1, 0, 0, 0);
    __builtin_amdgcn_s_setprio(0);
  };

#define LOADK4(d0, d1, d2, d3, tt)                                       \
  {                                                                      \
    const _Float16* kt = Kh + (size_t)(tt) * 2048 + lane * 8;            \
    d0 = *(const half8*)&kt[0];                                          \
    d1 = *(const half8*)&kt[512];                                        \
    d2 = *(const half8*)&kt[1024];                                       \
    d3 = *(const half8*)&kt[1536];                                       \
  }

  int t = w;
  if (t < tmax) {
    half8 k0, k1, k2, k3;
    LOADK4(k0, k1, k2, k3, t);
    for (;;) {
      const int tn = t + 4;
      const bool more = tn < tmax;
      half8 n0, n1, n2, n3;
      if (more) LOADK4(n0, n1, n2, n3, tn);       // K prefetch
      const _Float16* vt = Vh + (size_t)t * 2048 + lane * 8;
      half8 v0 = *(const half8*)&vt[0];
      half8 v1 = *(const half8*)&vt[512];
      half8 v2 = *(const half8*)&vt[1024];
      half8 v3 = *(const half8*)&vt[1536];
      f32x4 amv[4];
#pragma unroll
      for (int s4 = 0; s4 < 4; ++s4)
        amv[s4] = *(const f32x4*)&am[t * 32 + 8 * s4 + 4 * h];

      if (t < ntA)
        doStrip(oA0, oA1, lpA, qfA, limA, nfullA, t, k0, k1, k2, k3, v0, v1, v2, v3, amv);
      if (t < ntB)
        doStrip(oB0, oB1, lpB, qfB, limB, nfullB, t, k0, k1, k2, k3, v0, v1, v2, v3, amv);

      if (!more) break;
      k0 = n0; k1 = n1; k2 = n2; k3 = n3;
      t = tn;
    }
  }

  // ---- finish strips sequentially through shared LDS merge buffer ----
  auto finish = [&](f32x16& o0, f32x16& o1, f32x2* lp, int idx)
      __attribute__((always_inline)) {
    f32x2 s2 = (lp[0] + lp[1]) + (lp[2] + lp[3]);
    float lw = s2[0] + s2[1];
    lw += __shfl_xor(lw, 32);
    if (h == 0) lbuf[w][q31] = lw;
#pragma unroll
    for (int j = 0; j < 4; ++j) {
      half4 h0, h1;
#pragma unroll
      for (int e = 0; e < 4; ++e) {
        h0[e] = (_Float16)o0[4 * j + e];
        h1[e] = (_Float16)o1[4 * j + e];
      }
      *(half4*)&obuf[w][q31][4 * h + 8 * j]      = h0;
      *(half4*)&obuf[w][q31][32 + 4 * h + 8 * j] = h1;
    }
    __syncthreads();
    const int mq = tid >> 3;
    const int md = (tid & 7) * 8;
    const float lt = (lbuf[0][mq] + lbuf[1][mq]) + (lbuf[2][mq] + lbuf[3][mq]);
    float s[8];
    half8 p0 = *(const half8*)&obuf[0][mq][md];
#pragma unroll
    for (int e = 0; e < 8; ++e) s[e] = (float)p0[e];
#pragma unroll
    for (int w4 = 1; w4 < 4; ++w4) {
      half8 pw = *(const half8*)&obuf[w4][mq][md];
#pragma unroll
      for (int e = 0; e < 8; ++e) s[e] += (float)pw[e];
    }
    const float inv = 1.0f / lt;
    float4 s0, s1;
    s0.x = s[0] * inv; s0.y = s[1] * inv; s0.z = s[2] * inv; s0.w = s[3] * inv;
    s1.x = s[4] * inv; s1.y = s[5] * inv; s1.z = s[6] * inv; s1.w = s[7] * inv;
    float* op = out + ((size_t)(bI * S_LEN + idx * 32 + mq)) * 1024 + head * 64 + md;
    *(float4*)op = s0;
    *(float4*)(op + 4) = s1;
    __syncthreads();                    // protect obuf/lbuf for next strip
  };
  finish(oA0, oA1, lpA, idxA);
  finish(oB0, oB1, lpB, idxB);
}

// ---------------- launch --------------------------------------------------
extern "C" void kernel_launch(void* const* d_in, const int* in_sizes, int n_in,
                              void* d_out, int out_size, void* d_ws, size_t ws_size,
                              hipStream_t stream) {
  const float* hs = (const float*)d_in[0];
  const float* am = (const float*)d_in[1];
  const float* Wq = (const float*)d_in[2];
  const float* bq = (const float*)d_in[3];
  const float* Wk = (const float*)d_in[4];
  const float* bk = (const float*)d_in[5];
  const float* Wv = (const float*)d_in[6];
  const float* bv = (const float*)d_in[7];
  float* out = (float*)d_out;

  char* ws = (char*)d_ws;
  _Float16* hsb = (_Float16*)(ws);
  _Float16* wb  = (_Float16*)(ws + 8388608);
  _Float16* Qf  = (_Float16*)(ws + 14680064);
  _Float16* Kf  = (_Float16*)(ws + 23068672);
  _Float16* Vf  = (_Float16*)(ws + 31457280);

  convert_kernel<<<7168, 256, 0, stream>>>(
      (const float4*)hs, (const float4*)Wq, (const float4*)Wk, (const float4*)Wv, hsb, wb);
  qkv_gemm<<<768, 256, 0, stream>>>(hsb, wb, bq, bk, bv, Qf, Kf, Vf);
  attn_kernel<<<1024, 256, 0, stream>>>(Qf, Kf, Vf, am, out);
}

// Round 16
// 74.375 us; speedup vs baseline: 1.4237x; 1.1660x over previous
//
#include <hip/hip_runtime.h>

typedef float f32x2 __attribute__((ext_vector_type(2)));
typedef float f32x4 __attribute__((ext_vector_type(4)));
typedef float f32x16 __attribute__((ext_vector_type(16)));
typedef _Float16 half8 __attribute__((ext_vector_type(8)));
typedef _Float16 half4 __attribute__((ext_vector_type(4)));
typedef unsigned int u32;
typedef u32 u32x4 __attribute__((ext_vector_type(4)));

#define S_LEN 2048
#define NHEAD 16
#define HDIM 64
#define BATCH 2
#define WINDOW 512
#define M2_FIX 5.770780163555852f   /* 4.0 * log2(e) */
#define LOG2E 1.4426950408889634f

#define GLDS16(gp, lp) __builtin_amdgcn_global_load_lds( \
    (const __attribute__((address_space(1))) void*)(gp), \
    (__attribute__((address_space(3))) void*)(lp), 16, 0, 0)

// Fragment-packed layouts (per bh = b*16+head, stride 131072 halfs):
//  Q/K tile t: [ch(4)][lane(64)][j(8)]  lane=((d>>3)&1)*32+(s&31), ch=d>>4, j=d&7
//  V   tile t: [sub(4)][lane(64)][j(8)] sub=(d>>5)*2+((s>>4)&1),
//                                       lane=((s>>3)&1)*32+(d&31), j=s&7

// ---------------- kernel 1: convert hs + W(q,k,v) f32 -> f16 (r11) ----------
__global__ __launch_bounds__(256) void convert_kernel(
    const float4* __restrict__ hs, const float4* __restrict__ wq,
    const float4* __restrict__ wk, const float4* __restrict__ wv,
    _Float16* __restrict__ hsb, _Float16* __restrict__ wb) {
  int i = blockIdx.x * 256 + threadIdx.x;
  float4 v;
  _Float16* dst;
  if (i < 1048576) {
    v = hs[i];
    dst = hsb + (size_t)i * 4;
  } else {
    int j = i - 1048576;
    if (j < 262144) v = wq[j];
    else if (j < 524288) v = wk[j - 262144];
    else v = wv[j - 524288];
    dst = wb + (size_t)j * 4;
  }
  half4 o;
  o[0] = (_Float16)v.x; o[1] = (_Float16)v.y;
  o[2] = (_Float16)v.z; o[3] = (_Float16)v.w;
  *(half4*)dst = o;
}

// ---------------- kernel 2: QKV GEMM, 256x256, 8 waves, 8-phase-style -------
// Wave tile 128x64 (44 FLOP per LDS byte, 1.37x less LDS traffic than 128^2).
// Per K-tile: 4 phases {2 glds stage || ds_read quad -> lgkm(0) -> setprio ->
// 16 MFMA -> raw barrier}; one vmcnt(0)/tile (shallow: drains 4-phase-old).
__global__ __launch_bounds__(512, 2) void qkv_gemm(
    const _Float16* __restrict__ A, const _Float16* __restrict__ W,
    const float* __restrict__ bq, const float* __restrict__ bk,
    const float* __restrict__ bv,
    _Float16* __restrict__ Qf, _Float16* __restrict__ Kf, _Float16* __restrict__ Vf) {
  __shared__ _Float16 sbuf[65536];   // 128KB: A[2][256][64] | B[2][256][64]
  const int tid = threadIdx.x;
  const int wv = tid >> 6;           // 0..7
  const int lane = tid & 63;
  const int g = lane >> 4;
  const int c = lane & 15;
  const int bid = blockIdx.x;        // 192 blocks: m = bid&15 -> same-m same XCD
  const int m0 = (bid & 15) * 256;
  const int n0 = (bid >> 4) * 256;
  const int wm = wv >> 2;            // 0,1  (m half)
  const int wn = wv & 3;             // 0..3 (n quarter)

  // staging: thread covers row srow of each 64-row group, swizzled k-chunk
  const int srow = tid >> 3;                       // 0..63
  const int sk = ((tid & 7) ^ ((tid >> 3) & 7)) * 8;
  const _Float16* aSrc = A + (size_t)(m0 + srow) * 1024 + sk;
  const _Float16* bSrc = W + (size_t)(n0 + srow) * 1024 + sk;
  char* const ldsB = (char*)&sbuf[0];

  auto STAGE_A = [&](int bf_, int k0, int grp) __attribute__((always_inline)) {
    GLDS16(aSrc + (size_t)grp * 65536 + k0,
           ldsB + bf_ * 32768 + grp * 8192 + tid * 16);
  };
  auto STAGE_B = [&](int bf_, int k0, int grp) __attribute__((always_inline)) {
    GLDS16(bSrc + (size_t)grp * 65536 + k0,
           ldsB + 65536 + bf_ * 32768 + grp * 8192 + tid * 16);
  };

  // frag read bases (halfs): A row = wm*128 + mf*16 + c ; B row = wn*64 + nf*16 + c
  const int slot0 = ((0 * 4 + g) ^ (c & 7)) * 8;   // kk=0 chunk slot
  const int slot1 = ((1 * 4 + g) ^ (c & 7)) * 8;   // kk=1
  const int aRow = wm * 128 + c;
  const int bRow = wn * 64 + c;

  f32x4 acc[8][4];
#pragma unroll
  for (int i = 0; i < 8; ++i)
#pragma unroll
    for (int j = 0; j < 4; ++j) acc[i][j] = (f32x4){0.f, 0.f, 0.f, 0.f};

  // prologue: stage tile 0 fully, drain, barrier
#pragma unroll
  for (int grp = 0; grp < 4; ++grp) STAGE_A(0, 0, grp);
#pragma unroll
  for (int grp = 0; grp < 4; ++grp) STAGE_B(0, 0, grp);
  asm volatile("s_waitcnt vmcnt(0)" ::: "memory");
  __builtin_amdgcn_sched_barrier(0);
  __builtin_amdgcn_s_barrier();

  half8 bfr[4][2];
  for (int t = 0; t < 16; ++t) {
    const int bf = t & 1;
    const int abase = bf * 16384;
    const int bbase = 32768 + bf * 16384;
    const int kn = (t + 1) * 64;
    const bool st = t < 15;

#pragma unroll
    for (int p = 0; p < 4; ++p) {
      // stage schedule: p0: A-h0, p1: A-h1, p2: B-h0, p3: B-h1 (tile t+1)
      if (st) {
        if (p == 0)      { STAGE_A(bf ^ 1, kn, 0); STAGE_A(bf ^ 1, kn, 1); }
        else if (p == 1) { STAGE_A(bf ^ 1, kn, 2); STAGE_A(bf ^ 1, kn, 3); }
        else if (p == 2) { STAGE_B(bf ^ 1, kn, 0); STAGE_B(bf ^ 1, kn, 1); }
        else             { STAGE_B(bf ^ 1, kn, 2); STAGE_B(bf ^ 1, kn, 3); }
      }
      // ds_read: B all 8 frags on p==0 (held in regs); A quadrant (4 frags)
      if (p == 0) {
#pragma unroll
        for (int nf = 0; nf < 4; ++nf) {
          bfr[nf][0] = *(const half8*)&sbuf[bbase + (bRow + nf * 16) * 64 + slot0];
          bfr[nf][1] = *(const half8*)&sbuf[bbase + (bRow + nf * 16) * 64 + slot1];
        }
      }
      half8 aq[2][2];
#pragma unroll
      for (int mi = 0; mi < 2; ++mi) {
        const int row = aRow + (2 * p + mi) * 16;
        aq[mi][0] = *(const half8*)&sbuf[abase + row * 64 + slot0];
        aq[mi][1] = *(const half8*)&sbuf[abase + row * 64 + slot1];
      }
      asm volatile("s_waitcnt lgkmcnt(0)" ::: "memory");
      __builtin_amdgcn_sched_barrier(0);
      __builtin_amdgcn_s_setprio(1);
#pragma unroll
      for (int nf = 0; nf < 4; ++nf)
#pragma unroll
        for (int mi = 0; mi < 2; ++mi) {
          acc[2 * p + mi][nf] = __builtin_amdgcn_mfma_f32_16x16x32_f16(
              aq[mi][0], bfr[nf][0], acc[2 * p + mi][nf], 0, 0, 0);
          acc[2 * p + mi][nf] = __builtin_amdgcn_mfma_f32_16x16x32_f16(
              aq[mi][1], bfr[nf][1], acc[2 * p + mi][nf], 0, 0, 0);
        }
      __builtin_amdgcn_s_setprio(0);
      if (p == 3) {                      // tile boundary: next tile landed
        asm volatile("s_waitcnt vmcnt(0)" ::: "memory");
        __builtin_amdgcn_sched_barrier(0);
      }
      __builtin_amdgcn_s_barrier();
    }
  }

  // ---- epilogue: per-wave LDS bounce (16KB region), contiguous stores ----
  const int nAbs = n0 + wn * 64;
  const int kind = nAbs >> 10;              // 0=Q 1=K 2=V
  const int nb = nAbs & 1023;
  const int head = nb >> 6;
  const float* bias = kind == 0 ? bq : (kind == 1 ? bk : bv);
  _Float16* dst = kind == 0 ? Qf : (kind == 1 ? Kf : Vf);
  _Float16* ob = &sbuf[wv * 8192];

  if (kind < 2) {
    const float scl = kind == 0 ? (0.125f * LOG2E) : 1.0f;
#pragma unroll
    for (int nf = 0; nf < 4; ++nf) {
      const int d = nf * 16 + c;
      const float bsv = bias[nb + d];
      const int base = nf * 512 + ((c >> 3) & 1) * 256 + (c & 7);
#pragma unroll
      for (int mf = 0; mf < 8; ++mf) {
#pragma unroll
        for (int r = 0; r < 4; ++r) {
          ob[(mf >> 1) * 2048 + base + (mf & 1) * 128 + g * 32 + r * 8] =
              (_Float16)((acc[mf][nf][r] + bsv) * scl);
        }
      }
    }
  } else {
#pragma unroll
    for (int nf = 0; nf < 4; ++nf) {
      const int d = nf * 16 + c;
      const float bsv = bias[nb + d];
#pragma unroll
      for (int mf = 0; mf < 8; ++mf) {
        half4 v4;
#pragma unroll
        for (int r = 0; r < 4; ++r) v4[r] = (_Float16)(acc[mf][nf][r] + bsv);
        *(half4*)&ob[(mf >> 1) * 2048 + ((nf >> 1) * 2 + (mf & 1)) * 512 +
                     ((g >> 1) * 32 + (nf & 1) * 16 + c) * 8 + (g & 1) * 4] = v4;
      }
    }
  }

  // wave's 128 m-rows = 4 consecutive frag tiles = 16KB contiguous in dst
  const int mRow = m0 + wm * 128;
  const int bI = mRow >> 11;
  const size_t gbase = (size_t)(bI * NHEAD + head) * 131072 +
                       (size_t)((mRow & 2047) >> 5) * 2048;
#pragma unroll
  for (int i = 0; i < 16; ++i) {
    half8 v = *(const half8*)&ob[i * 512 + lane * 8];
    *(half8*)&dst[gbase + i * 512 + lane * 8] = v;
  }
}

// ---------------- kernel 3: windowed flash attention (r13 verbatim) ---------
__global__ __launch_bounds__(256) void attn_kernel(
    const _Float16* __restrict__ Qf, const _Float16* __restrict__ Kf,
    const _Float16* __restrict__ Vf, const float* __restrict__ amask,
    float* __restrict__ out) {
  __shared__ _Float16 obuf[4][32][72];
  __shared__ float lbuf[4][32];
  const int tid = threadIdx.x;
  const int w = tid >> 6;
  const int lane = tid & 63;
  const int q31 = lane & 31;
  const int h = lane >> 5;
  const int bid = blockIdx.x;
  const int bh = bid & 31;
  const int idx = 63 - (bid >> 5);  // longest strips launch first
  const int i0 = idx * 32;
  const int bI = bh >> 4;
  const int head = bh & 15;

  const _Float16* Qh = Qf + (size_t)bh * 131072;
  const _Float16* Kh = Kf + (size_t)bh * 131072;
  const _Float16* Vh = Vf + (size_t)bh * 131072;
  const float* am = amask + (size_t)bI * S_LEN;

  const int q = i0 + q31;
  const int hiq = (q <= WINDOW) ? q : (q - WINDOW - 1);
  const int last = i0 + 31;
  const int himax = (last <= WINDOW) ? last
                    : ((i0 <= WINDOW) ? WINDOW : (last - WINDOW - 1));
  const int hiq_min = (last <= WINDOW) ? i0
                      : ((i0 > WINDOW) ? (i0 - WINDOW - 1) : 0);
  const int ntiles = (himax >> 5) + 1;
  const int nfull = (hiq_min + 1) >> 5;
  const int lim = hiq - 4 * h;

  half8 qf[4];
#pragma unroll
  for (int ch = 0; ch < 4; ++ch)
    qf[ch] = *(const half8*)&Qh[(size_t)idx * 2048 + ch * 512 + lane * 8];

  f32x16 zero16, m2init;
#pragma unroll
  for (int r = 0; r < 16; ++r) { zero16[r] = 0.f; m2init[r] = -M2_FIX; }
  f32x16 oacc0 = zero16, oacc1 = zero16;
  f32x2 lp[4];
#pragma unroll
  for (int r = 0; r < 4; ++r) lp[r] = (f32x2){0.f, 0.f};

  auto computeTile = [&](half8 k0, half8 k1, half8 k2, half8 k3,
                         half8 vf0, half8 vf1, half8 vf2, half8 vf3,
                         f32x4 am0, f32x4 am1, f32x4 am2, f32x4 am3, int t)
      __attribute__((always_inline)) {
    const int j0 = t * 32;
    f32x4 amv[4] = {am0, am1, am2, am3};

    __builtin_amdgcn_s_setprio(1);
    f32x16 st = __builtin_amdgcn_mfma_f32_32x32x16_f16(k0, qf[0], m2init, 0, 0, 0);
    st = __builtin_amdgcn_mfma_f32_32x32x16_f16(k1, qf[1], st, 0, 0, 0);
    st = __builtin_amdgcn_mfma_f32_32x32x16_f16(k2, qf[2], st, 0, 0, 0);
    st = __builtin_amdgcn_mfma_f32_32x32x16_f16(k3, qf[3], st, 0, 0, 0);
    __builtin_amdgcn_s_setprio(0);

    float p[16];
#pragma unroll
    for (int r = 0; r < 16; ++r)
      p[r] = __builtin_fmaf(amv[r >> 2][r & 3], LOG2E, st[r]);
    if (t >= nfull) {
      const int lm = lim - j0;
#pragma unroll
      for (int r = 0; r < 16; ++r) {
        const int off = (r & 3) + 8 * (r >> 2);
        p[r] = (off <= lm) ? p[r] : -3e38f;
      }
    }
#pragma unroll
    for (int r = 0; r < 16; ++r) p[r] = __builtin_amdgcn_exp2f(p[r]);
#pragma unroll
    for (int j = 0; j < 4; ++j) {
      lp[j] += (f32x2){p[2 * j], p[2 * j + 1]};
      lp[j] += (f32x2){p[8 + 2 * j], p[9 + 2 * j]};
    }

    u32 pk[8];
#pragma unroll
    for (int r = 0; r < 8; ++r) {
      auto c2 = __builtin_amdgcn_cvt_pkrtz(p[2 * r], p[2 * r + 1]);
      pk[r] = __builtin_bit_cast(u32, c2);
    }
    u32 a0 = pk[0], b0 = pk[2];
    u32 a1 = pk[1], b1 = pk[3];
    u32 a2 = pk[4], b2 = pk[6];
    u32 a3 = pk[5], b3 = pk[7];
    asm("v_permlane32_swap_b32 %0, %1" : "+v"(a0), "+v"(b0));
    asm("v_permlane32_swap_b32 %0, %1" : "+v"(a1), "+v"(b1));
    asm("v_permlane32_swap_b32 %0, %1" : "+v"(a2), "+v"(b2));
    asm("v_permlane32_swap_b32 %0, %1" : "+v"(a3), "+v"(b3));
    const half8 pf0 = __builtin_bit_cast(half8, (u32x4){a0, a1, b0, b1});
    const half8 pf1 = __builtin_bit_cast(half8, (u32x4){a2, a3, b2, b3});

    __builtin_amdgcn_s_setprio(1);
    oacc0 = __builtin_amdgcn_mfma_f32_32x32x16_f16(vf0, pf0, oacc0, 0, 0, 0);
    oacc0 = __builtin_amdgcn_mfma_f32_32x32x16_f16(vf1, pf1, oacc0, 0, 0, 0);
    oacc1 = __builtin_amdgcn_mfma_f32_32x32x16_f16(vf2, pf0, oacc1, 0, 0, 0);
    oacc1 = __builtin_amdgcn_mfma_f32_32x32x16_f16(vf3, pf1, oacc1, 0, 0, 0);
    __builtin_amdgcn_s_setprio(0);
  };

#define LOADALL(k0, k1, k2, k3, v0, v1, v2, v3, a0_, a1_, a2_, a3_, tt)  \
  {                                                                      \
    const _Float16* kt = Kh + (size_t)(tt) * 2048 + lane * 8;            \
    const _Float16* vt = Vh + (size_t)(tt) * 2048 + lane * 8;            \
    const float* at = am + (tt) * 32 + 4 * h;                            \
    k0 = *(const half8*)&kt[0];                                          \
    k1 = *(const half8*)&kt[512];                                        \
    k2 = *(const half8*)&kt[1024];                                       \
    k3 = *(const half8*)&kt[1536];                                       \
    v0 = *(const half8*)&vt[0];                                          \
    v1 = *(const half8*)&vt[512];                                        \
    v2 = *(const half8*)&vt[1024];                                       \
    v3 = *(const half8*)&vt[1536];                                       \
    a0_ = *(const f32x4*)&at[0];                                         \
    a1_ = *(const f32x4*)&at[8];                                         \
    a2_ = *(const f32x4*)&at[16];                                        \
    a3_ = *(const f32x4*)&at[24];                                        \
  }

  int t = w;
  if (t < ntiles) {
    half8 k0, k1, k2, k3, v0, v1, v2, v3;
    f32x4 a0, a1, a2, a3;
    LOADALL(k0, k1, k2, k3, v0, v1, v2, v3, a0, a1, a2, a3, t);
    int tn = t + 4;
    while (tn < ntiles) {
      half8 n0, n1, n2, n3, u0, u1, u2, u3;
      f32x4 e0, e1, e2, e3;
      LOADALL(n0, n1, n2, n3, u0, u1, u2, u3, e0, e1, e2, e3, tn);
      computeTile(k0, k1, k2, k3, v0, v1, v2, v3, a0, a1, a2, a3, t);
      k0 = n0; k1 = n1; k2 = n2; k3 = n3;
      v0 = u0; v1 = u1; v2 = u2; v3 = u3;
      a0 = e0; a1 = e1; a2 = e2; a3 = e3;
      t = tn;
      tn += 4;
    }
    computeTile(k0, k1, k2, k3, v0, v1, v2, v3, a0, a1, a2, a3, t);
  }

  f32x2 s2 = (lp[0] + lp[1]) + (lp[2] + lp[3]);
  float lw = s2[0] + s2[1];
  lw += __shfl_xor(lw, 32);
  if (h == 0) lbuf[w][q31] = lw;
#pragma unroll
  for (int j = 0; j < 4; ++j) {
    half4 h0, h1;
#pragma unroll
    for (int e = 0; e < 4; ++e) {
      h0[e] = (_Float16)oacc0[4 * j + e];
      h1[e] = (_Float16)oacc1[4 * j + e];
    }
    *(half4*)&obuf[w][q31][4 * h + 8 * j]      = h0;
    *(half4*)&obuf[w][q31][32 + 4 * h + 8 * j] = h1;
  }
  __syncthreads();

  const int mq = tid >> 3;
  const int md = (tid & 7) * 8;
  const float lt = (lbuf[0][mq] + lbuf[1][mq]) + (lbuf[2][mq] + lbuf[3][mq]);
  float s[8];
  half8 p0 = *(const half8*)&obuf[0][mq][md];
#pragma unroll
  for (int e = 0; e < 8; ++e) s[e] = (float)p0[e];
#pragma unroll
  for (int w4 = 1; w4 < 4; ++w4) {
    half8 pw = *(const half8*)&obuf[w4][mq][md];
#pragma unroll
    for (int e = 0; e < 8; ++e) s[e] += (float)pw[e];
  }
  const float inv = 1.0f / lt;
  float4 s0, s1;
  s0.x = s[0] * inv; s0.y = s[1] * inv; s0.z = s[2] * inv; s0.w = s[3] * inv;
  s1.x = s[4] * inv; s1.y = s[5] * inv; s1.z = s[6] * inv; s1.w = s[7] * inv;
  float* op = out + ((size_t)(bI * S_LEN + i0 + mq)) * 1024 + head * 64 + md;
  *(float4*)op = s0;
  *(float4*)(op + 4) = s1;
}

// ---------------- launch --------------------------------------------------
extern "C" void kernel_launch(void* const* d_in, const int* in_sizes, int n_in,
                              void* d_out, int out_size, void* d_ws, size_t ws_size,
                              hipStream_t stream) {
  const float* hs = (const float*)d_in[0];
  const float* am = (const float*)d_in[1];
  const float* Wq = (const float*)d_in[2];
  const float* bq = (const float*)d_in[3];
  const float* Wk = (const float*)d_in[4];
  const float* bk = (const float*)d_in[5];
  const float* Wv = (const float*)d_in[6];
  const float* bv = (const float*)d_in[7];
  float* out = (float*)d_out;

  char* ws = (char*)d_ws;
  _Float16* hsb = (_Float16*)(ws);
  _Float16* wb  = (_Float16*)(ws + 8388608);
  _Float16* Qf  = (_Float16*)(ws + 14680064);
  _Float16* Kf  = (_Float16*)(ws + 23068672);
  _Float16* Vf  = (_Float16*)(ws + 31457280);

  convert_kernel<<<7168, 256, 0, stream>>>(
      (const float4*)hs, (const float4*)Wq, (const float4*)Wk, (const float4*)Wv, hsb, wb);
  qkv_gemm<<<192, 512, 0, stream>>>(hsb, wb, bq, bk, bv, Qf, Kf, Vf);
  attn_kernel<<<2048, 256, 0, stream>>>(Qf, Kf, Vf, am, out);
}

// Round 17
// 72.770 us; speedup vs baseline: 1.4551x; 1.0221x over previous
//
#include <hip/hip_runtime.h>

typedef float f32x2 __attribute__((ext_vector_type(2)));
typedef float f32x4 __attribute__((ext_vector_type(4)));
typedef float f32x16 __attribute__((ext_vector_type(16)));
typedef _Float16 half8 __attribute__((ext_vector_type(8)));
typedef _Float16 half4 __attribute__((ext_vector_type(4)));
typedef unsigned int u32;
typedef u32 u32x4 __attribute__((ext_vector_type(4)));

#define S_LEN 2048
#define NHEAD 16
#define HDIM 64
#define BATCH 2
#define WINDOW 512
#define M2_FIX 5.770780163555852f   /* 4.0 * log2(e) */
#define LOG2E 1.4426950408889634f

#define GLDS16(gp, lp) __builtin_amdgcn_global_load_lds( \
    (const __attribute__((address_space(1))) void*)(gp), \
    (__attribute__((address_space(3))) void*)(lp), 16, 0, 0)

// Fragment-packed layouts (per bh = b*16+head, stride 131072 halfs):
//  Q/K tile t: [ch(4)][lane(64)][j(8)]  lane=((d>>3)&1)*32+(s&31), ch=d>>4, j=d&7
//  V   tile t: [sub(4)][lane(64)][j(8)] sub=(d>>5)*2+((s>>4)&1),
//                                       lane=((s>>3)&1)*32+(d&31), j=s&7

// ---------------- kernel 1: convert hs + W(q,k,v) f32 -> f16 (r11) ----------
__global__ __launch_bounds__(256) void convert_kernel(
    const float4* __restrict__ hs, const float4* __restrict__ wq,
    const float4* __restrict__ wk, const float4* __restrict__ wv,
    _Float16* __restrict__ hsb, _Float16* __restrict__ wb) {
  int i = blockIdx.x * 256 + threadIdx.x;
  float4 v;
  _Float16* dst;
  if (i < 1048576) {
    v = hs[i];
    dst = hsb + (size_t)i * 4;
  } else {
    int j = i - 1048576;
    if (j < 262144) v = wq[j];
    else if (j < 524288) v = wk[j - 262144];
    else v = wv[j - 524288];
    dst = wb + (size_t)j * 4;
  }
  half4 o;
  o[0] = (_Float16)v.x; o[1] = (_Float16)v.y;
  o[2] = (_Float16)v.z; o[3] = (_Float16)v.w;
  *(half4*)dst = o;
}

// ---------------- kernel 2: QKV GEMM, 256x256, 8 waves, 8-phase-style -------
// Stage schedule: ALL of tile t+1's 8 glds issue in phases 0-1, so the p3
// vmcnt(0) finds them long-landed (2-3 MFMA phases of cover).
__global__ __launch_bounds__(512, 2) void qkv_gemm(
    const _Float16* __restrict__ A, const _Float16* __restrict__ W,
    const float* __restrict__ bq, const float* __restrict__ bk,
    const float* __restrict__ bv,
    _Float16* __restrict__ Qf, _Float16* __restrict__ Kf, _Float16* __restrict__ Vf) {
  __shared__ _Float16 sbuf[65536];   // 128KB: A[2][256][64] | B[2][256][64]
  const int tid = threadIdx.x;
  const int wv = tid >> 6;           // 0..7
  const int lane = tid & 63;
  const int g = lane >> 4;
  const int c = lane & 15;
  const int bid = blockIdx.x;        // 192 blocks: m = bid&15 -> same-m same XCD
  const int m0 = (bid & 15) * 256;
  const int n0 = (bid >> 4) * 256;
  const int wm = wv >> 2;            // 0,1  (m half)
  const int wn = wv & 3;             // 0..3 (n quarter)

  // staging: thread covers row srow of each 64-row group, swizzled k-chunk
  const int srow = tid >> 3;                       // 0..63
  const int sk = ((tid & 7) ^ ((tid >> 3) & 7)) * 8;
  const _Float16* aSrc = A + (size_t)(m0 + srow) * 1024 + sk;
  const _Float16* bSrc = W + (size_t)(n0 + srow) * 1024 + sk;
  char* const ldsB = (char*)&sbuf[0];

  auto STAGE_A = [&](int bf_, int k0, int grp) __attribute__((always_inline)) {
    GLDS16(aSrc + (size_t)grp * 65536 + k0,
           ldsB + bf_ * 32768 + grp * 8192 + tid * 16);
  };
  auto STAGE_B = [&](int bf_, int k0, int grp) __attribute__((always_inline)) {
    GLDS16(bSrc + (size_t)grp * 65536 + k0,
           ldsB + 65536 + bf_ * 32768 + grp * 8192 + tid * 16);
  };

  // frag read bases (halfs): A row = wm*128 + mf*16 + c ; B row = wn*64 + nf*16 + c
  const int slot0 = ((0 * 4 + g) ^ (c & 7)) * 8;   // kk=0 chunk slot
  const int slot1 = ((1 * 4 + g) ^ (c & 7)) * 8;   // kk=1
  const int aRow = wm * 128 + c;
  const int bRow = wn * 64 + c;

  f32x4 acc[8][4];
#pragma unroll
  for (int i = 0; i < 8; ++i)
#pragma unroll
    for (int j = 0; j < 4; ++j) acc[i][j] = (f32x4){0.f, 0.f, 0.f, 0.f};

  // prologue: stage tile 0 fully, drain, barrier
#pragma unroll
  for (int grp = 0; grp < 4; ++grp) STAGE_A(0, 0, grp);
#pragma unroll
  for (int grp = 0; grp < 4; ++grp) STAGE_B(0, 0, grp);
  asm volatile("s_waitcnt vmcnt(0)" ::: "memory");
  __builtin_amdgcn_sched_barrier(0);
  __builtin_amdgcn_s_barrier();

  half8 bfr[4][2];
  for (int t = 0; t < 16; ++t) {
    const int bf = t & 1;
    const int abase = bf * 16384;
    const int bbase = 32768 + bf * 16384;
    const int kn = (t + 1) * 64;
    const bool st = t < 15;

#pragma unroll
    for (int p = 0; p < 4; ++p) {
      // stage schedule: ALL 8 glds of tile t+1 in p0 (A) and p1 (B)
      if (st) {
        if (p == 0) {
          STAGE_A(bf ^ 1, kn, 0); STAGE_A(bf ^ 1, kn, 1);
          STAGE_A(bf ^ 1, kn, 2); STAGE_A(bf ^ 1, kn, 3);
        } else if (p == 1) {
          STAGE_B(bf ^ 1, kn, 0); STAGE_B(bf ^ 1, kn, 1);
          STAGE_B(bf ^ 1, kn, 2); STAGE_B(bf ^ 1, kn, 3);
        }
      }
      // ds_read: B all 8 frags on p==0 (held in regs); A quadrant (4 frags)
      if (p == 0) {
#pragma unroll
        for (int nf = 0; nf < 4; ++nf) {
          bfr[nf][0] = *(const half8*)&sbuf[bbase + (bRow + nf * 16) * 64 + slot0];
          bfr[nf][1] = *(const half8*)&sbuf[bbase + (bRow + nf * 16) * 64 + slot1];
        }
      }
      half8 aq[2][2];
#pragma unroll
      for (int mi = 0; mi < 2; ++mi) {
        const int row = aRow + (2 * p + mi) * 16;
        aq[mi][0] = *(const half8*)&sbuf[abase + row * 64 + slot0];
        aq[mi][1] = *(const half8*)&sbuf[abase + row * 64 + slot1];
      }
      asm volatile("s_waitcnt lgkmcnt(0)" ::: "memory");
      __builtin_amdgcn_sched_barrier(0);
      __builtin_amdgcn_s_setprio(1);
#pragma unroll
      for (int nf = 0; nf < 4; ++nf)
#pragma unroll
        for (int mi = 0; mi < 2; ++mi) {
          acc[2 * p + mi][nf] = __builtin_amdgcn_mfma_f32_16x16x32_f16(
              aq[mi][0], bfr[nf][0], acc[2 * p + mi][nf], 0, 0, 0);
          acc[2 * p + mi][nf] = __builtin_amdgcn_mfma_f32_16x16x32_f16(
              aq[mi][1], bfr[nf][1], acc[2 * p + mi][nf], 0, 0, 0);
        }
      __builtin_amdgcn_s_setprio(0);
      if (p == 3) {                      // tile boundary: loads long-landed
        asm volatile("s_waitcnt vmcnt(0)" ::: "memory");
        __builtin_amdgcn_sched_barrier(0);
      }
      __builtin_amdgcn_s_barrier();
    }
  }

  // ---- epilogue: per-wave LDS bounce (16KB region), contiguous stores ----
  const int nAbs = n0 + wn * 64;
  const int kind = nAbs >> 10;              // 0=Q 1=K 2=V
  const int nb = nAbs & 1023;
  const int head = nb >> 6;
  const float* bias = kind == 0 ? bq : (kind == 1 ? bk : bv);
  _Float16* dst = kind == 0 ? Qf : (kind == 1 ? Kf : Vf);
  _Float16* ob = &sbuf[wv * 8192];

  if (kind < 2) {
    const float scl = kind == 0 ? (0.125f * LOG2E) : 1.0f;
#pragma unroll
    for (int nf = 0; nf < 4; ++nf) {
      const int d = nf * 16 + c;
      const float bsv = bias[nb + d];
      const int base = nf * 512 + ((c >> 3) & 1) * 256 + (c & 7);
#pragma unroll
      for (int mf = 0; mf < 8; ++mf) {
#pragma unroll
        for (int r = 0; r < 4; ++r) {
          ob[(mf >> 1) * 2048 + base + (mf & 1) * 128 + g * 32 + r * 8] =
              (_Float16)((acc[mf][nf][r] + bsv) * scl);
        }
      }
    }
  } else {
#pragma unroll
    for (int nf = 0; nf < 4; ++nf) {
      const int d = nf * 16 + c;
      const float bsv = bias[nb + d];
#pragma unroll
      for (int mf = 0; mf < 8; ++mf) {
        half4 v4;
#pragma unroll
        for (int r = 0; r < 4; ++r) v4[r] = (_Float16)(acc[mf][nf][r] + bsv);
        *(half4*)&ob[(mf >> 1) * 2048 + ((nf >> 1) * 2 + (mf & 1)) * 512 +
                     ((g >> 1) * 32 + (nf & 1) * 16 + c) * 8 + (g & 1) * 4] = v4;
      }
    }
  }

  // wave's 128 m-rows = 4 consecutive frag tiles = 16KB contiguous in dst
  const int mRow = m0 + wm * 128;
  const int bI = mRow >> 11;
  const size_t gbase = (size_t)(bI * NHEAD + head) * 131072 +
                       (size_t)((mRow & 2047) >> 5) * 2048;
#pragma unroll
  for (int i = 0; i < 16; ++i) {
    half8 v = *(const half8*)&ob[i * 512 + lane * 8];
    *(half8*)&dst[gbase + i * 512 + lane * 8] = v;
  }
}

// ---------------- kernel 3: windowed flash attention (r13 verbatim) ---------
__global__ __launch_bounds__(256) void attn_kernel(
    const _Float16* __restrict__ Qf, const _Float16* __restrict__ Kf,
    const _Float16* __restrict__ Vf, const float* __restrict__ amask,
    float* __restrict__ out) {
  __shared__ _Float16 obuf[4][32][72];
  __shared__ float lbuf[4][32];
  const int tid = threadIdx.x;
  const int w = tid >> 6;
  const int lane = tid & 63;
  const int q31 = lane & 31;
  const int h = lane >> 5;
  const int bid = blockIdx.x;
  const int bh = bid & 31;
  const int idx = 63 - (bid >> 5);  // longest strips launch first
  const int i0 = idx * 32;
  const int bI = bh >> 4;
  const int head = bh & 15;

  const _Float16* Qh = Qf + (size_t)bh * 131072;
  const _Float16* Kh = Kf + (size_t)bh * 131072;
  const _Float16* Vh = Vf + (size_t)bh * 131072;
  const float* am = amask + (size_t)bI * S_LEN;

  const int q = i0 + q31;
  const int hiq = (q <= WINDOW) ? q : (q - WINDOW - 1);
  const int last = i0 + 31;
  const int himax = (last <= WINDOW) ? last
                    : ((i0 <= WINDOW) ? WINDOW : (last - WINDOW - 1));
  const int hiq_min = (last <= WINDOW) ? i0
                      : ((i0 > WINDOW) ? (i0 - WINDOW - 1) : 0);
  const int ntiles = (himax >> 5) + 1;
  const int nfull = (hiq_min + 1) >> 5;
  const int lim = hiq - 4 * h;

  half8 qf[4];
#pragma unroll
  for (int ch = 0; ch < 4; ++ch)
    qf[ch] = *(const half8*)&Qh[(size_t)idx * 2048 + ch * 512 + lane * 8];

  f32x16 zero16, m2init;
#pragma unroll
  for (int r = 0; r < 16; ++r) { zero16[r] = 0.f; m2init[r] = -M2_FIX; }
  f32x16 oacc0 = zero16, oacc1 = zero16;
  f32x2 lp[4];
#pragma unroll
  for (int r = 0; r < 4; ++r) lp[r] = (f32x2){0.f, 0.f};

  auto computeTile = [&](half8 k0, half8 k1, half8 k2, half8 k3,
                         half8 vf0, half8 vf1, half8 vf2, half8 vf3,
                         f32x4 am0, f32x4 am1, f32x4 am2, f32x4 am3, int t)
      __attribute__((always_inline)) {
    const int j0 = t * 32;
    f32x4 amv[4] = {am0, am1, am2, am3};

    __builtin_amdgcn_s_setprio(1);
    f32x16 st = __builtin_amdgcn_mfma_f32_32x32x16_f16(k0, qf[0], m2init, 0, 0, 0);
    st = __builtin_amdgcn_mfma_f32_32x32x16_f16(k1, qf[1], st, 0, 0, 0);
    st = __builtin_amdgcn_mfma_f32_32x32x16_f16(k2, qf[2], st, 0, 0, 0);
    st = __builtin_amdgcn_mfma_f32_32x32x16_f16(k3, qf[3], st, 0, 0, 0);
    __builtin_amdgcn_s_setprio(0);

    float p[16];
#pragma unroll
    for (int r = 0; r < 16; ++r)
      p[r] = __builtin_fmaf(amv[r >> 2][r & 3], LOG2E, st[r]);
    if (t >= nfull) {
      const int lm = lim - j0;
#pragma unroll
      for (int r = 0; r < 16; ++r) {
        const int off = (r & 3) + 8 * (r >> 2);
        p[r] = (off <= lm) ? p[r] : -3e38f;
      }
    }
#pragma unroll
    for (int r = 0; r < 16; ++r) p[r] = __builtin_amdgcn_exp2f(p[r]);
#pragma unroll
    for (int j = 0; j < 4; ++j) {
      lp[j] += (f32x2){p[2 * j], p[2 * j + 1]};
      lp[j] += (f32x2){p[8 + 2 * j], p[9 + 2 * j]};
    }

    u32 pk[8];
#pragma unroll
    for (int r = 0; r < 8; ++r) {
      auto c2 = __builtin_amdgcn_cvt_pkrtz(p[2 * r], p[2 * r + 1]);
      pk[r] = __builtin_bit_cast(u32, c2);
    }
    u32 a0 = pk[0], b0 = pk[2];
    u32 a1 = pk[1], b1 = pk[3];
    u32 a2 = pk[4], b2 = pk[6];
    u32 a3 = pk[5], b3 = pk[7];
    asm("v_permlane32_swap_b32 %0, %1" : "+v"(a0), "+v"(b0));
    asm("v_permlane32_swap_b32 %0, %1" : "+v"(a1), "+v"(b1));
    asm("v_permlane32_swap_b32 %0, %1" : "+v"(a2), "+v"(b2));
    asm("v_permlane32_swap_b32 %0, %1" : "+v"(a3), "+v"(b3));
    const half8 pf0 = __builtin_bit_cast(half8, (u32x4){a0, a1, b0, b1});
    const half8 pf1 = __builtin_bit_cast(half8, (u32x4){a2, a3, b2, b3});

    __builtin_amdgcn_s_setprio(1);
    oacc0 = __builtin_amdgcn_mfma_f32_32x32x16_f16(vf0, pf0, oacc0, 0, 0, 0);
    oacc0 = __builtin_amdgcn_mfma_f32_32x32x16_f16(vf1, pf1, oacc0, 0, 0, 0);
    oacc1 = __builtin_amdgcn_mfma_f32_32x32x16_f16(vf2, pf0, oacc1, 0, 0, 0);
    oacc1 = __builtin_amdgcn_mfma_f32_32x32x16_f16(vf3, pf1, oacc1, 0, 0, 0);
    __builtin_amdgcn_s_setprio(0);
  };

#define LOADALL(k0, k1, k2, k3, v0, v1, v2, v3, a0_, a1_, a2_, a3_, tt)  \
  {                                                                      \
    const _Float16* kt = Kh + (size_t)(tt) * 2048 + lane * 8;            \
    const _Float16* vt = Vh + (size_t)(tt) * 2048 + lane * 8;            \
    const float* at = am + (tt) * 32 + 4 * h;                            \
    k0 = *(const half8*)&kt[0];                                          \
    k1 = *(const half8*)&kt[512];                                        \
    k2 = *(const half8*)&kt[1024];                                       \
    k3 = *(const half8*)&kt[1536];                                       \
    v0 = *(const half8*)&vt[0];                                          \
    v1 = *(const half8*)&vt[512];                                        \
    v2 = *(const half8*)&vt[1024];                                       \
    v3 = *(const half8*)&vt[1536];                                       \
    a0_ = *(const f32x4*)&at[0];                                         \
    a1_ = *(const f32x4*)&at[8];                                         \
    a2_ = *(const f32x4*)&at[16];                                        \
    a3_ = *(const f32x4*)&at[24];                                        \
  }

  int t = w;
  if (t < ntiles) {
    half8 k0, k1, k2, k3, v0, v1, v2, v3;
    f32x4 a0, a1, a2, a3;
    LOADALL(k0, k1, k2, k3, v0, v1, v2, v3, a0, a1, a2, a3, t);
    int tn = t + 4;
    while (tn < ntiles) {
      half8 n0, n1, n2, n3, u0, u1, u2, u3;
      f32x4 e0, e1, e2, e3;
      LOADALL(n0, n1, n2, n3, u0, u1, u2, u3, e0, e1, e2, e3, tn);
      computeTile(k0, k1, k2, k3, v0, v1, v2, v3, a0, a1, a2, a3, t);
      k0 = n0; k1 = n1; k2 = n2; k3 = n3;
      v0 = u0; v1 = u1; v2 = u2; v3 = u3;
      a0 = e0; a1 = e1; a2 = e2; a3 = e3;
      t = tn;
      tn += 4;
    }
    computeTile(k0, k1, k2, k3, v0, v1, v2, v3, a0, a1, a2, a3, t);
  }

  f32x2 s2 = (lp[0] + lp[1]) + (lp[2] + lp[3]);
  float lw = s2[0] + s2[1];
  lw += __shfl_xor(lw, 32);
  if (h == 0) lbuf[w][q31] = lw;
#pragma unroll
  for (int j = 0; j < 4; ++j) {
    half4 h0, h1;
#pragma unroll
    for (int e = 0; e < 4; ++e) {
      h0[e] = (_Float16)oacc0[4 * j + e];
      h1[e] = (_Float16)oacc1[4 * j + e];
    }
    *(half4*)&obuf[w][q31][4 * h + 8 * j]      = h0;
    *(half4*)&obuf[w][q31][32 + 4 * h + 8 * j] = h1;
  }
  __syncthreads();

  const int mq = tid >> 3;
  const int md = (tid & 7) * 8;
  const float lt = (lbuf[0][mq] + lbuf[1][mq]) + (lbuf[2][mq] + lbuf[3][mq]);
  float s[8];
  half8 p0 = *(const half8*)&obuf[0][mq][md];
#pragma unroll
  for (int e = 0; e < 8; ++e) s[e] = (float)p0[e];
#pragma unroll
  for (int w4 = 1; w4 < 4; ++w4) {
    half8 pw = *(const half8*)&obuf[w4][mq][md];
#pragma unroll
    for (int e = 0; e < 8; ++e) s[e] += (float)pw[e];
  }
  const float inv = 1.0f / lt;
  float4 s0, s1;
  s0.x = s[0] * inv; s0.y = s[1] * inv; s0.z = s[2] * inv; s0.w = s[3] * inv;
  s1.x = s[4] * inv; s1.y = s[5] * inv; s1.z = s[6] * inv; s1.w = s[7] * inv;
  float* op = out + ((size_t)(bI * S_LEN + i0 + mq)) * 1024 + head * 64 + md;
  *(float4*)op = s0;
  *(float4*)(op + 4) = s1;
}

// ---------------- launch --------------------------------------------------
extern "C" void kernel_launch(void* const* d_in, const int* in_sizes, int n_in,
                              void* d_out, int out_size, void* d_ws, size_t ws_size,
                              hipStream_t stream) {
  const float* hs = (const float*)d_in[0];
  const float* am = (const float*)d_in[1];
  const float* Wq = (const float*)d_in[2];
  const float* bq = (const float*)d_in[3];
  const float* Wk = (const float*)d_in[4];
  const float* bk = (const float*)d_in[5];
  const float* Wv = (const float*)d_in[6];
  const float* bv = (const float*)d_in[7];
  float* out = (float*)d_out;

  char* ws = (char*)d_ws;
  _Float16* hsb = (_Float16*)(ws);
  _Float16* wb  = (_Float16*)(ws + 8388608);
  _Float16* Qf  = (_Float16*)(ws + 14680064);
  _Float16* Kf  = (_Float16*)(ws + 23068672);
  _Float16* Vf  = (_Float16*)(ws + 31457280);

  convert_kernel<<<7168, 256, 0, stream>>>(
      (const float4*)hs, (const float4*)Wq, (const float4*)Wk, (const float4*)Wv, hsb, wb);
  qkv_gemm<<<192, 512, 0, stream>>>(hsb, wb, bq, bk, bv, Qf, Kf, Vf);
  attn_kernel<<<2048, 256, 0, stream>>>(Qf, Kf, Vf, am, out);
}

// Round 18
// 70.655 us; speedup vs baseline: 1.4986x; 1.0299x over previous
//
#include <hip/hip_runtime.h>

typedef float f32x2 __attribute__((ext_vector_type(2)));
typedef float f32x4 __attribute__((ext_vector_type(4)));
typedef float f32x16 __attribute__((ext_vector_type(16)));
typedef _Float16 half8 __attribute__((ext_vector_type(8)));
typedef _Float16 half4 __attribute__((ext_vector_type(4)));
typedef unsigned int u32;
typedef u32 u32x4 __attribute__((ext_vector_type(4)));

#define S_LEN 2048
#define NHEAD 16
#define HDIM 64
#define BATCH 2
#define WINDOW 512
#define M2_FIX 5.770780163555852f   /* 4.0 * log2(e) */
#define LOG2E 1.4426950408889634f

#define GLDS16(gp, lp) __builtin_amdgcn_global_load_lds( \
    (const __attribute__((address_space(1))) void*)(gp), \
    (__attribute__((address_space(3))) void*)(lp), 16, 0, 0)

// Fragment-packed layouts (per bh = b*16+head, stride 131072 halfs):
//  Q/K tile t: [ch(4)][lane(64)][j(8)]  lane=((d>>3)&1)*32+(s&31), ch=d>>4, j=d&7
//  V   tile t: [sub(4)][lane(64)][j(8)] sub=(d>>5)*2+((s>>4)&1),
//                                       lane=((s>>3)&1)*32+(d&31), j=s&7

// ---------------- kernel 1: convert hs + W(q,k,v) f32 -> f16 (r11) ----------
__global__ __launch_bounds__(256) void convert_kernel(
    const float4* __restrict__ hs, const float4* __restrict__ wq,
    const float4* __restrict__ wk, const float4* __restrict__ wv,
    _Float16* __restrict__ hsb, _Float16* __restrict__ wb) {
  int i = blockIdx.x * 256 + threadIdx.x;
  float4 v;
  _Float16* dst;
  if (i < 1048576) {
    v = hs[i];
    dst = hsb + (size_t)i * 4;
  } else {
    int j = i - 1048576;
    if (j < 262144) v = wq[j];
    else if (j < 524288) v = wk[j - 262144];
    else v = wv[j - 524288];
    dst = wb + (size_t)j * 4;
  }
  half4 o;
  o[0] = (_Float16)v.x; o[1] = (_Float16)v.y;
  o[2] = (_Float16)v.z; o[3] = (_Float16)v.w;
  *(half4*)dst = o;
}

// ---------------- kernel 2: QKV GEMM, 256x256, 8 waves, 1-barrier/tile ------
// All 8 glds of tile t+1 issue in phases 0-1 (3 MFMA phases of cover).
// ONLY barrier per K-tile is at p3 (after vmcnt(0)): waves desynchronize
// within a tile, so one wave's MFMA covers another's ds_read (role split).
__global__ __launch_bounds__(512, 2) void qkv_gemm(
    const _Float16* __restrict__ A, const _Float16* __restrict__ W,
    const float* __restrict__ bq, const float* __restrict__ bk,
    const float* __restrict__ bv,
    _Float16* __restrict__ Qf, _Float16* __restrict__ Kf, _Float16* __restrict__ Vf) {
  __shared__ _Float16 sbuf[65536];   // 128KB: A[2][256][64] | B[2][256][64]
  const int tid = threadIdx.x;
  const int wv = tid >> 6;           // 0..7
  const int lane = tid & 63;
  const int g = lane >> 4;
  const int c = lane & 15;
  const int bid = blockIdx.x;        // 192 blocks: m = bid&15 -> same-m same XCD
  const int m0 = (bid & 15) * 256;
  const int n0 = (bid >> 4) * 256;
  const int wm = wv >> 2;            // 0,1  (m half)
  const int wn = wv & 3;             // 0..3 (n quarter)

  // staging: thread covers row srow of each 64-row group, swizzled k-chunk
  const int srow = tid >> 3;                       // 0..63
  const int sk = ((tid & 7) ^ ((tid >> 3) & 7)) * 8;
  const _Float16* aSrc = A + (size_t)(m0 + srow) * 1024 + sk;
  const _Float16* bSrc = W + (size_t)(n0 + srow) * 1024 + sk;
  char* const ldsB = (char*)&sbuf[0];

  auto STAGE_A = [&](int bf_, int k0, int grp) __attribute__((always_inline)) {
    GLDS16(aSrc + (size_t)grp * 65536 + k0,
           ldsB + bf_ * 32768 + grp * 8192 + tid * 16);
  };
  auto STAGE_B = [&](int bf_, int k0, int grp) __attribute__((always_inline)) {
    GLDS16(bSrc + (size_t)grp * 65536 + k0,
           ldsB + 65536 + bf_ * 32768 + grp * 8192 + tid * 16);
  };

  // frag read bases (halfs): A row = wm*128 + mf*16 + c ; B row = wn*64 + nf*16 + c
  const int slot0 = ((0 * 4 + g) ^ (c & 7)) * 8;   // kk=0 chunk slot
  const int slot1 = ((1 * 4 + g) ^ (c & 7)) * 8;   // kk=1
  const int aRow = wm * 128 + c;
  const int bRow = wn * 64 + c;

  f32x4 acc[8][4];
#pragma unroll
  for (int i = 0; i < 8; ++i)
#pragma unroll
    for (int j = 0; j < 4; ++j) acc[i][j] = (f32x4){0.f, 0.f, 0.f, 0.f};

  // prologue: stage tile 0 fully, drain, barrier
#pragma unroll
  for (int grp = 0; grp < 4; ++grp) STAGE_A(0, 0, grp);
#pragma unroll
  for (int grp = 0; grp < 4; ++grp) STAGE_B(0, 0, grp);
  asm volatile("s_waitcnt vmcnt(0)" ::: "memory");
  __builtin_amdgcn_sched_barrier(0);
  __builtin_amdgcn_s_barrier();

  half8 bfr[4][2];
  for (int t = 0; t < 16; ++t) {
    const int bf = t & 1;
    const int abase = bf * 16384;
    const int bbase = 32768 + bf * 16384;
    const int kn = (t + 1) * 64;
    const bool st = t < 15;

#pragma unroll
    for (int p = 0; p < 4; ++p) {
      // stage schedule: ALL 8 glds of tile t+1 in p0 (A) and p1 (B)
      if (st) {
        if (p == 0) {
          STAGE_A(bf ^ 1, kn, 0); STAGE_A(bf ^ 1, kn, 1);
          STAGE_A(bf ^ 1, kn, 2); STAGE_A(bf ^ 1, kn, 3);
        } else if (p == 1) {
          STAGE_B(bf ^ 1, kn, 0); STAGE_B(bf ^ 1, kn, 1);
          STAGE_B(bf ^ 1, kn, 2); STAGE_B(bf ^ 1, kn, 3);
        }
      }
      // ds_read: B all 8 frags on p==0 (held in regs); A quadrant (4 frags)
      if (p == 0) {
#pragma unroll
        for (int nf = 0; nf < 4; ++nf) {
          bfr[nf][0] = *(const half8*)&sbuf[bbase + (bRow + nf * 16) * 64 + slot0];
          bfr[nf][1] = *(const half8*)&sbuf[bbase + (bRow + nf * 16) * 64 + slot1];
        }
      }
      half8 aq[2][2];
#pragma unroll
      for (int mi = 0; mi < 2; ++mi) {
        const int row = aRow + (2 * p + mi) * 16;
        aq[mi][0] = *(const half8*)&sbuf[abase + row * 64 + slot0];
        aq[mi][1] = *(const half8*)&sbuf[abase + row * 64 + slot1];
      }
      asm volatile("s_waitcnt lgkmcnt(0)" ::: "memory");
      __builtin_amdgcn_sched_barrier(0);
      __builtin_amdgcn_s_setprio(1);
#pragma unroll
      for (int nf = 0; nf < 4; ++nf)
#pragma unroll
        for (int mi = 0; mi < 2; ++mi) {
          acc[2 * p + mi][nf] = __builtin_amdgcn_mfma_f32_16x16x32_f16(
              aq[mi][0], bfr[nf][0], acc[2 * p + mi][nf], 0, 0, 0);
          acc[2 * p + mi][nf] = __builtin_amdgcn_mfma_f32_16x16x32_f16(
              aq[mi][1], bfr[nf][1], acc[2 * p + mi][nf], 0, 0, 0);
        }
      __builtin_amdgcn_s_setprio(0);
      if (p == 3) {                      // ONLY barrier per tile
        asm volatile("s_waitcnt vmcnt(0)" ::: "memory");
        __builtin_amdgcn_sched_barrier(0);
        __builtin_amdgcn_s_barrier();
      }
    }
  }

  // ---- epilogue: per-wave LDS bounce (16KB region), contiguous stores ----
  const int nAbs = n0 + wn * 64;
  const int kind = nAbs >> 10;              // 0=Q 1=K 2=V
  const int nb = nAbs & 1023;
  const int head = nb >> 6;
  const float* bias = kind == 0 ? bq : (kind == 1 ? bk : bv);
  _Float16* dst = kind == 0 ? Qf : (kind == 1 ? Kf : Vf);
  _Float16* ob = &sbuf[wv * 8192];

  if (kind < 2) {
    const float scl = kind == 0 ? (0.125f * LOG2E) : 1.0f;
#pragma unroll
    for (int nf = 0; nf < 4; ++nf) {
      const int d = nf * 16 + c;
      const float bsv = bias[nb + d];
      const int base = nf * 512 + ((c >> 3) & 1) * 256 + (c & 7);
#pragma unroll
      for (int mf = 0; mf < 8; ++mf) {
#pragma unroll
        for (int r = 0; r < 4; ++r) {
          ob[(mf >> 1) * 2048 + base + (mf & 1) * 128 + g * 32 + r * 8] =
              (_Float16)((acc[mf][nf][r] + bsv) * scl);
        }
      }
    }
  } else {
#pragma unroll
    for (int nf = 0; nf < 4; ++nf) {
      const int d = nf * 16 + c;
      const float bsv = bias[nb + d];
#pragma unroll
      for (int mf = 0; mf < 8; ++mf) {
        half4 v4;
#pragma unroll
        for (int r = 0; r < 4; ++r) v4[r] = (_Float16)(acc[mf][nf][r] + bsv);
        *(half4*)&ob[(mf >> 1) * 2048 + ((nf >> 1) * 2 + (mf & 1)) * 512 +
                     ((g >> 1) * 32 + (nf & 1) * 16 + c) * 8 + (g & 1) * 4] = v4;
      }
    }
  }

  // wave's 128 m-rows = 4 consecutive frag tiles = 16KB contiguous in dst
  const int mRow = m0 + wm * 128;
  const int bI = mRow >> 11;
  const size_t gbase = (size_t)(bI * NHEAD + head) * 131072 +
                       (size_t)((mRow & 2047) >> 5) * 2048;
#pragma unroll
  for (int i = 0; i < 16; ++i) {
    half8 v = *(const half8*)&ob[i * 512 + lane * 8];
    *(half8*)&dst[gbase + i * 512 + lane * 8] = v;
  }
}

// ---------------- kernel 3: windowed flash attention (r13 verbatim) ---------
__global__ __launch_bounds__(256) void attn_kernel(
    const _Float16* __restrict__ Qf, const _Float16* __restrict__ Kf,
    const _Float16* __restrict__ Vf, const float* __restrict__ amask,
    float* __restrict__ out) {
  __shared__ _Float16 obuf[4][32][72];
  __shared__ float lbuf[4][32];
  const int tid = threadIdx.x;
  const int w = tid >> 6;
  const int lane = tid & 63;
  const int q31 = lane & 31;
  const int h = lane >> 5;
  const int bid = blockIdx.x;
  const int bh = bid & 31;
  const int idx = 63 - (bid >> 5);  // longest strips launch first
  const int i0 = idx * 32;
  const int bI = bh >> 4;
  const int head = bh & 15;

  const _Float16* Qh = Qf + (size_t)bh * 131072;
  const _Float16* Kh = Kf + (size_t)bh * 131072;
  const _Float16* Vh = Vf + (size_t)bh * 131072;
  const float* am = amask + (size_t)bI * S_LEN;

  const int q = i0 + q31;
  const int hiq = (q <= WINDOW) ? q : (q - WINDOW - 1);
  const int last = i0 + 31;
  const int himax = (last <= WINDOW) ? last
                    : ((i0 <= WINDOW) ? WINDOW : (last - WINDOW - 1));
  const int hiq_min = (last <= WINDOW) ? i0
                      : ((i0 > WINDOW) ? (i0 - WINDOW - 1) : 0);
  const int ntiles = (himax >> 5) + 1;
  const int nfull = (hiq_min + 1) >> 5;
  const int lim = hiq - 4 * h;

  half8 qf[4];
#pragma unroll
  for (int ch = 0; ch < 4; ++ch)
    qf[ch] = *(const half8*)&Qh[(size_t)idx * 2048 + ch * 512 + lane * 8];

  f32x16 zero16, m2init;
#pragma unroll
  for (int r = 0; r < 16; ++r) { zero16[r] = 0.f; m2init[r] = -M2_FIX; }
  f32x16 oacc0 = zero16, oacc1 = zero16;
  f32x2 lp[4];
#pragma unroll
  for (int r = 0; r < 4; ++r) lp[r] = (f32x2){0.f, 0.f};

  auto computeTile = [&](half8 k0, half8 k1, half8 k2, half8 k3,
                         half8 vf0, half8 vf1, half8 vf2, half8 vf3,
                         f32x4 am0, f32x4 am1, f32x4 am2, f32x4 am3, int t)
      __attribute__((always_inline)) {
    const int j0 = t * 32;
    f32x4 amv[4] = {am0, am1, am2, am3};

    __builtin_amdgcn_s_setprio(1);
    f32x16 st = __builtin_amdgcn_mfma_f32_32x32x16_f16(k0, qf[0], m2init, 0, 0, 0);
    st = __builtin_amdgcn_mfma_f32_32x32x16_f16(k1, qf[1], st, 0, 0, 0);
    st = __builtin_amdgcn_mfma_f32_32x32x16_f16(k2, qf[2], st, 0, 0, 0);
    st = __builtin_amdgcn_mfma_f32_32x32x16_f16(k3, qf[3], st, 0, 0, 0);
    __builtin_amdgcn_s_setprio(0);

    float p[16];
#pragma unroll
    for (int r = 0; r < 16; ++r)
      p[r] = __builtin_fmaf(amv[r >> 2][r & 3], LOG2E, st[r]);
    if (t >= nfull) {
      const int lm = lim - j0;
#pragma unroll
      for (int r = 0; r < 16; ++r) {
        const int off = (r & 3) + 8 * (r >> 2);
        p[r] = (off <= lm) ? p[r] : -3e38f;
      }
    }
#pragma unroll
    for (int r = 0; r < 16; ++r) p[r] = __builtin_amdgcn_exp2f(p[r]);
#pragma unroll
    for (int j = 0; j < 4; ++j) {
      lp[j] += (f32x2){p[2 * j], p[2 * j + 1]};
      lp[j] += (f32x2){p[8 + 2 * j], p[9 + 2 * j]};
    }

    u32 pk[8];
#pragma unroll
    for (int r = 0; r < 8; ++r) {
      auto c2 = __builtin_amdgcn_cvt_pkrtz(p[2 * r], p[2 * r + 1]);
      pk[r] = __builtin_bit_cast(u32, c2);
    }
    u32 a0 = pk[0], b0 = pk[2];
    u32 a1 = pk[1], b1 = pk[3];
    u32 a2 = pk[4], b2 = pk[6];
    u32 a3 = pk[5], b3 = pk[7];
    asm("v_permlane32_swap_b32 %0, %1" : "+v"(a0), "+v"(b0));
    asm("v_permlane32_swap_b32 %0, %1" : "+v"(a1), "+v"(b1));
    asm("v_permlane32_swap_b32 %0, %1" : "+v"(a2), "+v"(b2));
    asm("v_permlane32_swap_b32 %0, %1" : "+v"(a3), "+v"(b3));
    const half8 pf0 = __builtin_bit_cast(half8, (u32x4){a0, a1, b0, b1});
    const half8 pf1 = __builtin_bit_cast(half8, (u32x4){a2, a3, b2, b3});

    __builtin_amdgcn_s_setprio(1);
    oacc0 = __builtin_amdgcn_mfma_f32_32x32x16_f16(vf0, pf0, oacc0, 0, 0, 0);
    oacc0 = __builtin_amdgcn_mfma_f32_32x32x16_f16(vf1, pf1, oacc0, 0, 0, 0);
    oacc1 = __builtin_amdgcn_mfma_f32_32x32x16_f16(vf2, pf0, oacc1, 0, 0, 0);
    oacc1 = __builtin_amdgcn_mfma_f32_32x32x16_f16(vf3, pf1, oacc1, 0, 0, 0);
    __builtin_amdgcn_s_setprio(0);
  };

#define LOADALL(k0, k1, k2, k3, v0, v1, v2, v3, a0_, a1_, a2_, a3_, tt)  \
  {                                                                      \
    const _Float16* kt = Kh + (size_t)(tt) * 2048 + lane * 8;            \
    const _Float16* vt = Vh + (size_t)(tt) * 2048 + lane * 8;            \
    const float* at = am + (tt) * 32 + 4 * h;                            \
    k0 = *(const half8*)&kt[0];                                          \
    k1 = *(const half8*)&kt[512];                                        \
    k2 = *(const half8*)&kt[1024];                                       \
    k3 = *(const half8*)&kt[1536];                                       \
    v0 = *(const half8*)&vt[0];                                          \
    v1 = *(const half8*)&vt[512];                                        \
    v2 = *(const half8*)&vt[1024];                                       \
    v3 = *(const half8*)&vt[1536];                                       \
    a0_ = *(const f32x4*)&at[0];                                         \
    a1_ = *(const f32x4*)&at[8];                                         \
    a2_ = *(const f32x4*)&at[16];                                        \
    a3_ = *(const f32x4*)&at[24];                                        \
  }

  int t = w;
  if (t < ntiles) {
    half8 k0, k1, k2, k3, v0, v1, v2, v3;
    f32x4 a0, a1, a2, a3;
    LOADALL(k0, k1, k2, k3, v0, v1, v2, v3, a0, a1, a2, a3, t);
    int tn = t + 4;
    while (tn < ntiles) {
      half8 n0, n1, n2, n3, u0, u1, u2, u3;
      f32x4 e0, e1, e2, e3;
      LOADALL(n0, n1, n2, n3, u0, u1, u2, u3, e0, e1, e2, e3, tn);
      computeTile(k0, k1, k2, k3, v0, v1, v2, v3, a0, a1, a2, a3, t);
      k0 = n0; k1 = n1; k2 = n2; k3 = n3;
      v0 = u0; v1 = u1; v2 = u2; v3 = u3;
      a0 = e0; a1 = e1; a2 = e2; a3 = e3;
      t = tn;
      tn += 4;
    }
    computeTile(k0, k1, k2, k3, v0, v1, v2, v3, a0, a1, a2, a3, t);
  }

  f32x2 s2 = (lp[0] + lp[1]) + (lp[2] + lp[3]);
  float lw = s2[0] + s2[1];
  lw += __shfl_xor(lw, 32);
  if (h == 0) lbuf[w][q31] = lw;
#pragma unroll
  for (int j = 0; j < 4; ++j) {
    half4 h0, h1;
#pragma unroll
    for (int e = 0; e < 4; ++e) {
      h0[e] = (_Float16)oacc0[4 * j + e];
      h1[e] = (_Float16)oacc1[4 * j + e];
    }
    *(half4*)&obuf[w][q31][4 * h + 8 * j]      = h0;
    *(half4*)&obuf[w][q31][32 + 4 * h + 8 * j] = h1;
  }
  __syncthreads();

  const int mq = tid >> 3;
  const int md = (tid & 7) * 8;
  const float lt = (lbuf[0][mq] + lbuf[1][mq]) + (lbuf[2][mq] + lbuf[3][mq]);
  float s[8];
  half8 p0 = *(const half8*)&obuf[0][mq][md];
#pragma unroll
  for (int e = 0; e < 8; ++e) s[e] = (float)p0[e];
#pragma unroll
  for (int w4 = 1; w4 < 4; ++w4) {
    half8 pw = *(const half8*)&obuf[w4][mq][md];
#pragma unroll
    for (int e = 0; e < 8; ++e) s[e] += (float)pw[e];
  }
  const float inv = 1.0f / lt;
  float4 s0, s1;
  s0.x = s[0] * inv; s0.y = s[1] * inv; s0.z = s[2] * inv; s0.w = s[3] * inv;
  s1.x = s[4] * inv; s1.y = s[5] * inv; s1.z = s[6] * inv; s1.w = s[7] * inv;
  float* op = out + ((size_t)(bI * S_LEN + i0 + mq)) * 1024 + head * 64 + md;
  *(float4*)op = s0;
  *(float4*)(op + 4) = s1;
}

// ---------------- launch --------------------------------------------------
extern "C" void kernel_launch(void* const* d_in, const int* in_sizes, int n_in,
                              void* d_out, int out_size, void* d_ws, size_t ws_size,
                              hipStream_t stream) {
  const float* hs = (const float*)d_in[0];
  const float* am = (const float*)d_in[1];
  const float* Wq = (const float*)d_in[2];
  const float* bq = (const float*)d_in[3];
  const float* Wk = (const float*)d_in[4];
  const float* bk = (const float*)d_in[5];
  const float* Wv = (const float*)d_in[6];
  const float* bv = (const float*)d_in[7];
  float* out = (float*)d_out;

  char* ws = (char*)d_ws;
  _Float16* hsb = (_Float16*)(ws);
  _Float16* wb  = (_Float16*)(ws + 8388608);
  _Float16* Qf  = (_Float16*)(ws + 14680064);
  _Float16* Kf  = (_Float16*)(ws + 23068672);
  _Float16* Vf  = (_Float16*)(ws + 31457280);

  convert_kernel<<<7168, 256, 0, stream>>>(
      (const float4*)hs, (const float4*)Wq, (const float4*)Wk, (const float4*)Wv, hsb, wb);
  qkv_gemm<<<192, 512, 0, stream>>>(hsb, wb, bq, bk, bv, Qf, Kf, Vf);
  attn_kernel<<<2048, 256, 0, stream>>>(Qf, Kf, Vf, am, out);
}

// Round 19
// 70.353 us; speedup vs baseline: 1.5051x; 1.0043x over previous
//
#include <hip/hip_runtime.h>

typedef float f32x2 __attribute__((ext_vector_type(2)));
typedef float f32x4 __attribute__((ext_vector_type(4)));
typedef float f32x16 __attribute__((ext_vector_type(16)));
typedef _Float16 half8 __attribute__((ext_vector_type(8)));
typedef _Float16 half4 __attribute__((ext_vector_type(4)));
typedef unsigned int u32;
typedef u32 u32x4 __attribute__((ext_vector_type(4)));

#define S_LEN 2048
#define NHEAD 16
#define HDIM 64
#define BATCH 2
#define WINDOW 512
#define M2_FIX 5.770780163555852f   /* 4.0 * log2(e) */
#define LOG2E 1.4426950408889634f

#define GLDS16(gp, lp) __builtin_amdgcn_global_load_lds( \
    (const __attribute__((address_space(1))) void*)(gp), \
    (__attribute__((address_space(3))) void*)(lp), 16, 0, 0)

// Fragment-packed layouts (per bh = b*16+head, stride 131072 halfs):
//  Q/K tile t: [ch(4)][lane(64)][j(8)]  lane=((d>>3)&1)*32+(s&31), ch=d>>4, j=d&7
//  V   tile t: [sub(4)][lane(64)][j(8)] sub=(d>>5)*2+((s>>4)&1),
//                                       lane=((s>>3)&1)*32+(d&31), j=s&7

// ---------------- kernel 1: convert hs + W(q,k,v) f32 -> f16 (r11) ----------
__global__ __launch_bounds__(256) void convert_kernel(
    const float4* __restrict__ hs, const float4* __restrict__ wq,
    const float4* __restrict__ wk, const float4* __restrict__ wv,
    _Float16* __restrict__ hsb, _Float16* __restrict__ wb) {
  int i = blockIdx.x * 256 + threadIdx.x;
  float4 v;
  _Float16* dst;
  if (i < 1048576) {
    v = hs[i];
    dst = hsb + (size_t)i * 4;
  } else {
    int j = i - 1048576;
    if (j < 262144) v = wq[j];
    else if (j < 524288) v = wk[j - 262144];
    else v = wv[j - 524288];
    dst = wb + (size_t)j * 4;
  }
  half4 o;
  o[0] = (_Float16)v.x; o[1] = (_Float16)v.y;
  o[2] = (_Float16)v.z; o[3] = (_Float16)v.w;
  *(half4*)dst = o;
}

// ---------------- kernel 2: QKV GEMM, 256x256, 8 waves, pipelined phases ----
// Next phase's A ds_reads issue BEFORE current phase's MFMA cluster; no
// hand-written per-phase lgkmcnt (compiler emits counted waits) -> LDS port
// and MFMA pipe overlap. One vmcnt(0)+barrier per K-tile (dbuf safety).
__global__ __launch_bounds__(512, 2) void qkv_gemm(
    const _Float16* __restrict__ A, const _Float16* __restrict__ W,
    const float* __restrict__ bq, const float* __restrict__ bk,
    const float* __restrict__ bv,
    _Float16* __restrict__ Qf, _Float16* __restrict__ Kf, _Float16* __restrict__ Vf) {
  __shared__ _Float16 sbuf[65536];   // 128KB: A[2][256][64] | B[2][256][64]
  const int tid = threadIdx.x;
  const int wv = tid >> 6;           // 0..7
  const int lane = tid & 63;
  const int g = lane >> 4;
  const int c = lane & 15;
  const int bid = blockIdx.x;        // 192 blocks: m = bid&15 -> same-m same XCD
  const int m0 = (bid & 15) * 256;
  const int n0 = (bid >> 4) * 256;
  const int wm = wv >> 2;            // 0,1  (m half)
  const int wn = wv & 3;             // 0..3 (n quarter)

  // staging: thread covers row srow of each 64-row group, swizzled k-chunk
  const int srow = tid >> 3;                       // 0..63
  const int sk = ((tid & 7) ^ ((tid >> 3) & 7)) * 8;
  const _Float16* aSrc = A + (size_t)(m0 + srow) * 1024 + sk;
  const _Float16* bSrc = W + (size_t)(n0 + srow) * 1024 + sk;
  char* const ldsB = (char*)&sbuf[0];

  auto STAGE_A = [&](int bf_, int k0, int grp) __attribute__((always_inline)) {
    GLDS16(aSrc + (size_t)grp * 65536 + k0,
           ldsB + bf_ * 32768 + grp * 8192 + tid * 16);
  };
  auto STAGE_B = [&](int bf_, int k0, int grp) __attribute__((always_inline)) {
    GLDS16(bSrc + (size_t)grp * 65536 + k0,
           ldsB + 65536 + bf_ * 32768 + grp * 8192 + tid * 16);
  };

  // frag read bases (halfs): A row = wm*128 + mf*16 + c ; B row = wn*64 + nf*16 + c
  const int slot0 = ((0 * 4 + g) ^ (c & 7)) * 8;   // kk=0 chunk slot
  const int slot1 = ((4 + g) ^ (c & 7)) * 8;       // kk=1
  const int aRow = wm * 128 + c;
  const int bRow = wn * 64 + c;

  f32x4 acc[8][4];
#pragma unroll
  for (int i = 0; i < 8; ++i)
#pragma unroll
    for (int j = 0; j < 4; ++j) acc[i][j] = (f32x4){0.f, 0.f, 0.f, 0.f};

  // prologue: stage tile 0 fully, drain, barrier
#pragma unroll
  for (int grp = 0; grp < 4; ++grp) STAGE_A(0, 0, grp);
#pragma unroll
  for (int grp = 0; grp < 4; ++grp) STAGE_B(0, 0, grp);
  asm volatile("s_waitcnt vmcnt(0)" ::: "memory");
  __builtin_amdgcn_sched_barrier(0);
  __builtin_amdgcn_s_barrier();

#define READA(dstv, ph)                                                       \
  {                                                                           \
    _Pragma("unroll") for (int mi = 0; mi < 2; ++mi) {                        \
      const int row = aRow + (2 * (ph) + mi) * 16;                            \
      dstv[mi][0] = *(const half8*)&sbuf[abase + row * 64 + slot0];           \
      dstv[mi][1] = *(const half8*)&sbuf[abase + row * 64 + slot1];           \
    }                                                                         \
  }
#define MFMAP(ph, srcv)                                                       \
  {                                                                           \
    __builtin_amdgcn_s_setprio(1);                                            \
    _Pragma("unroll") for (int nf = 0; nf < 4; ++nf)                          \
        _Pragma("unroll") for (int mi = 0; mi < 2; ++mi) {                    \
      acc[2 * (ph) + mi][nf] = __builtin_amdgcn_mfma_f32_16x16x32_f16(        \
          srcv[mi][0], bfr[nf][0], acc[2 * (ph) + mi][nf], 0, 0, 0);          \
      acc[2 * (ph) + mi][nf] = __builtin_amdgcn_mfma_f32_16x16x32_f16(        \
          srcv[mi][1], bfr[nf][1], acc[2 * (ph) + mi][nf], 0, 0, 0);          \
    }                                                                         \
    __builtin_amdgcn_s_setprio(0);                                            \
  }

  half8 bfr[4][2], aqA[2][2], aqB[2][2];
  for (int t = 0; t < 16; ++t) {
    const int bf = t & 1;
    const int abase = bf * 16384;
    const int bbase = 32768 + bf * 16384;
    const int kn = (t + 1) * 64;
    const bool st = t < 15;

    // issue B frags (whole tile) + A frags for phase 0
#pragma unroll
    for (int nf = 0; nf < 4; ++nf) {
      bfr[nf][0] = *(const half8*)&sbuf[bbase + (bRow + nf * 16) * 64 + slot0];
      bfr[nf][1] = *(const half8*)&sbuf[bbase + (bRow + nf * 16) * 64 + slot1];
    }
    READA(aqA, 0);
    // p0: stage A(t+1), prefetch A(p1), compute p0
    if (st) {
      STAGE_A(bf ^ 1, kn, 0); STAGE_A(bf ^ 1, kn, 1);
      STAGE_A(bf ^ 1, kn, 2); STAGE_A(bf ^ 1, kn, 3);
    }
    READA(aqB, 1);
    MFMAP(0, aqA);
    // p1: stage B(t+1), prefetch A(p2), compute p1
    if (st) {
      STAGE_B(bf ^ 1, kn, 0); STAGE_B(bf ^ 1, kn, 1);
      STAGE_B(bf ^ 1, kn, 2); STAGE_B(bf ^ 1, kn, 3);
    }
    READA(aqA, 2);
    MFMAP(1, aqB);
    // p2: prefetch A(p3), compute p2
    READA(aqB, 3);
    MFMAP(2, aqA);
    // p3: compute p3
    MFMAP(3, aqB);

    asm volatile("s_waitcnt vmcnt(0)" ::: "memory");   // tile t+1 landed
    __builtin_amdgcn_sched_barrier(0);
    __builtin_amdgcn_s_barrier();                       // dbuf safety
  }

  // ---- epilogue: per-wave LDS bounce (16KB region), contiguous stores ----
  const int nAbs = n0 + wn * 64;
  const int kind = nAbs >> 10;              // 0=Q 1=K 2=V
  const int nb = nAbs & 1023;
  const int head = nb >> 6;
  const float* bias = kind == 0 ? bq : (kind == 1 ? bk : bv);
  _Float16* dst = kind == 0 ? Qf : (kind == 1 ? Kf : Vf);
  _Float16* ob = &sbuf[wv * 8192];

  if (kind < 2) {
    const float scl = kind == 0 ? (0.125f * LOG2E) : 1.0f;
#pragma unroll
    for (int nf = 0; nf < 4; ++nf) {
      const int d = nf * 16 + c;
      const float bsv = bias[nb + d];
      const int base = nf * 512 + ((c >> 3) & 1) * 256 + (c & 7);
#pragma unroll
      for (int mf = 0; mf < 8; ++mf) {
#pragma unroll
        for (int r = 0; r < 4; ++r) {
          ob[(mf >> 1) * 2048 + base + (mf & 1) * 128 + g * 32 + r * 8] =
              (_Float16)((acc[mf][nf][r] + bsv) * scl);
        }
      }
    }
  } else {
#pragma unroll
    for (int nf = 0; nf < 4; ++nf) {
      const int d = nf * 16 + c;
      const float bsv = bias[nb + d];
#pragma unroll
      for (int mf = 0; mf < 8; ++mf) {
        half4 v4;
#pragma unroll
        for (int r = 0; r < 4; ++r) v4[r] = (_Float16)(acc[mf][nf][r] + bsv);
        *(half4*)&ob[(mf >> 1) * 2048 + ((nf >> 1) * 2 + (mf & 1)) * 512 +
                     ((g >> 1) * 32 + (nf & 1) * 16 + c) * 8 + (g & 1) * 4] = v4;
      }
    }
  }

  // wave's 128 m-rows = 4 consecutive frag tiles = 16KB contiguous in dst
  const int mRow = m0 + wm * 128;
  const int bI = mRow >> 11;
  const size_t gbase = (size_t)(bI * NHEAD + head) * 131072 +
                       (size_t)((mRow & 2047) >> 5) * 2048;
#pragma unroll
  for (int i = 0; i < 16; ++i) {
    half8 v = *(const half8*)&ob[i * 512 + lane * 8];
    *(half8*)&dst[gbase + i * 512 + lane * 8] = v;
  }
}

// ---------------- kernel 3: windowed flash attention (r13 verbatim) ---------
__global__ __launch_bounds__(256) void attn_kernel(
    const _Float16* __restrict__ Qf, const _Float16* __restrict__ Kf,
    const _Float16* __restrict__ Vf, const float* __restrict__ amask,
    float* __restrict__ out) {
  __shared__ _Float16 obuf[4][32][72];
  __shared__ float lbuf[4][32];
  const int tid = threadIdx.x;
  const int w = tid >> 6;
  const int lane = tid & 63;
  const int q31 = lane & 31;
  const int h = lane >> 5;
  const int bid = blockIdx.x;
  const int bh = bid & 31;
  const int idx = 63 - (bid >> 5);  // longest strips launch first
  const int i0 = idx * 32;
  const int bI = bh >> 4;
  const int head = bh & 15;

  const _Float16* Qh = Qf + (size_t)bh * 131072;
  const _Float16* Kh = Kf + (size_t)bh * 131072;
  const _Float16* Vh = Vf + (size_t)bh * 131072;
  const float* am = amask + (size_t)bI * S_LEN;

  const int q = i0 + q31;
  const int hiq = (q <= WINDOW) ? q : (q - WINDOW - 1);
  const int last = i0 + 31;
  const int himax = (last <= WINDOW) ? last
                    : ((i0 <= WINDOW) ? WINDOW : (last - WINDOW - 1));
  const int hiq_min = (last <= WINDOW) ? i0
                      : ((i0 > WINDOW) ? (i0 - WINDOW - 1) : 0);
  const int ntiles = (himax >> 5) + 1;
  const int nfull = (hiq_min + 1) >> 5;
  const int lim = hiq - 4 * h;

  half8 qf[4];
#pragma unroll
  for (int ch = 0; ch < 4; ++ch)
    qf[ch] = *(const half8*)&Qh[(size_t)idx * 2048 + ch * 512 + lane * 8];

  f32x16 zero16, m2init;
#pragma unroll
  for (int r = 0; r < 16; ++r) { zero16[r] = 0.f; m2init[r] = -M2_FIX; }
  f32x16 oacc0 = zero16, oacc1 = zero16;
  f32x2 lp[4];
#pragma unroll
  for (int r = 0; r < 4; ++r) lp[r] = (f32x2){0.f, 0.f};

  auto computeTile = [&](half8 k0, half8 k1, half8 k2, half8 k3,
                         half8 vf0, half8 vf1, half8 vf2, half8 vf3,
                         f32x4 am0, f32x4 am1, f32x4 am2, f32x4 am3, int t)
      __attribute__((always_inline)) {
    const int j0 = t * 32;
    f32x4 amv[4] = {am0, am1, am2, am3};

    __builtin_amdgcn_s_setprio(1);
    f32x16 st = __builtin_amdgcn_mfma_f32_32x32x16_f16(k0, qf[0], m2init, 0, 0, 0);
    st = __builtin_amdgcn_mfma_f32_32x32x16_f16(k1, qf[1], st, 0, 0, 0);
    st = __builtin_amdgcn_mfma_f32_32x32x16_f16(k2, qf[2], st, 0, 0, 0);
    st = __builtin_amdgcn_mfma_f32_32x32x16_f16(k3, qf[3], st, 0, 0, 0);
    __builtin_amdgcn_s_setprio(0);

    float p[16];
#pragma unroll
    for (int r = 0; r < 16; ++r)
      p[r] = __builtin_fmaf(amv[r >> 2][r & 3], LOG2E, st[r]);
    if (t >= nfull) {
      const int lm = lim - j0;
#pragma unroll
      for (int r = 0; r < 16; ++r) {
        const int off = (r & 3) + 8 * (r >> 2);
        p[r] = (off <= lm) ? p[r] : -3e38f;
      }
    }
#pragma unroll
    for (int r = 0; r < 16; ++r) p[r] = __builtin_amdgcn_exp2f(p[r]);
#pragma unroll
    for (int j = 0; j < 4; ++j) {
      lp[j] += (f32x2){p[2 * j], p[2 * j + 1]};
      lp[j] += (f32x2){p[8 + 2 * j], p[9 + 2 * j]};
    }

    u32 pk[8];
#pragma unroll
    for (int r = 0; r < 8; ++r) {
      auto c2 = __builtin_amdgcn_cvt_pkrtz(p[2 * r], p[2 * r + 1]);
      pk[r] = __builtin_bit_cast(u32, c2);
    }
    u32 a0 = pk[0], b0 = pk[2];
    u32 a1 = pk[1], b1 = pk[3];
    u32 a2 = pk[4], b2 = pk[6];
    u32 a3 = pk[5], b3 = pk[7];
    asm("v_permlane32_swap_b32 %0, %1" : "+v"(a0), "+v"(b0));
    asm("v_permlane32_swap_b32 %0, %1" : "+v"(a1), "+v"(b1));
    asm("v_permlane32_swap_b32 %0, %1" : "+v"(a2), "+v"(b2));
    asm("v_permlane32_swap_b32 %0, %1" : "+v"(a3), "+v"(b3));
    const half8 pf0 = __builtin_bit_cast(half8, (u32x4){a0, a1, b0, b1});
    const half8 pf1 = __builtin_bit_cast(half8, (u32x4){a2, a3, b2, b3});

    __builtin_amdgcn_s_setprio(1);
    oacc0 = __builtin_amdgcn_mfma_f32_32x32x16_f16(vf0, pf0, oacc0, 0, 0, 0);
    oacc0 = __builtin_amdgcn_mfma_f32_32x32x16_f16(vf1, pf1, oacc0, 0, 0, 0);
    oacc1 = __builtin_amdgcn_mfma_f32_32x32x16_f16(vf2, pf0, oacc1, 0, 0, 0);
    oacc1 = __builtin_amdgcn_mfma_f32_32x32x16_f16(vf3, pf1, oacc1, 0, 0, 0);
    __builtin_amdgcn_s_setprio(0);
  };

#define LOADALL(k0, k1, k2, k3, v0, v1, v2, v3, a0_, a1_, a2_, a3_, tt)  \
  {                                                                      \
    const _Float16* kt = Kh + (size_t)(tt) * 2048 + lane * 8;            \
    const _Float16* vt = Vh + (size_t)(tt) * 2048 + lane * 8;            \
    const float* at = am + (tt) * 32 + 4 * h;                            \
    k0 = *(const half8*)&kt[0];                                          \
    k1 = *(const half8*)&kt[512];                                        \
    k2 = *(const half8*)&kt[1024];                                       \
    k3 = *(const half8*)&kt[1536];                                       \
    v0 = *(const half8*)&vt[0];                                          \
    v1 = *(const half8*)&vt[512];                                        \
    v2 = *(const half8*)&vt[1024];                                       \
    v3 = *(const half8*)&vt[1536];                                       \
    a0_ = *(const f32x4*)&at[0];                                         \
    a1_ = *(const f32x4*)&at[8];                                         \
    a2_ = *(const f32x4*)&at[16];                                        \
    a3_ = *(const f32x4*)&at[24];                                        \
  }

  int t = w;
  if (t < ntiles) {
    half8 k0, k1, k2, k3, v0, v1, v2, v3;
    f32x4 a0, a1, a2, a3;
    LOADALL(k0, k1, k2, k3, v0, v1, v2, v3, a0, a1, a2, a3, t);
    int tn = t + 4;
    while (tn < ntiles) {
      half8 n0, n1, n2, n3, u0, u1, u2, u3;
      f32x4 e0, e1, e2, e3;
      LOADALL(n0, n1, n2, n3, u0, u1, u2, u3, e0, e1, e2, e3, tn);
      computeTile(k0, k1, k2, k3, v0, v1, v2, v3, a0, a1, a2, a3, t);
      k0 = n0; k1 = n1; k2 = n2; k3 = n3;
      v0 = u0; v1 = u1; v2 = u2; v3 = u3;
      a0 = e0; a1 = e1; a2 = e2; a3 = e3;
      t = tn;
      tn += 4;
    }
    computeTile(k0, k1, k2, k3, v0, v1, v2, v3, a0, a1, a2, a3, t);
  }

  f32x2 s2 = (lp[0] + lp[1]) + (lp[2] + lp[3]);
  float lw = s2[0] + s2[1];
  lw += __shfl_xor(lw, 32);
  if (h == 0) lbuf[w][q31] = lw;
#pragma unroll
  for (int j = 0; j < 4; ++j) {
    half4 h0, h1;
#pragma unroll
    for (int e = 0; e < 4; ++e) {
      h0[e] = (_Float16)oacc0[4 * j + e];
      h1[e] = (_Float16)oacc1[4 * j + e];
    }
    *(half4*)&obuf[w][q31][4 * h + 8 * j]      = h0;
    *(half4*)&obuf[w][q31][32 + 4 * h + 8 * j] = h1;
  }
  __syncthreads();

  const int mq = tid >> 3;
  const int md = (tid & 7) * 8;
  const float lt = (lbuf[0][mq] + lbuf[1][mq]) + (lbuf[2][mq] + lbuf[3][mq]);
  float s[8];
  half8 p0 = *(const half8*)&obuf[0][mq][md];
#pragma unroll
  for (int e = 0; e < 8; ++e) s[e] = (float)p0[e];
#pragma unroll
  for (int w4 = 1; w4 < 4; ++w4) {
    half8 pw = *(const half8*)&obuf[w4][mq][md];
#pragma unroll
    for (int e = 0; e < 8; ++e) s[e] += (float)pw[e];
  }
  const float inv = 1.0f / lt;
  float4 s0, s1;
  s0.x = s[0] * inv; s0.y = s[1] * inv; s0.z = s[2] * inv; s0.w = s[3] * inv;
  s1.x = s[4] * inv; s1.y = s[5] * inv; s1.z = s[6] * inv; s1.w = s[7] * inv;
  float* op = out + ((size_t)(bI * S_LEN + i0 + mq)) * 1024 + head * 64 + md;
  *(float4*)op = s0;
  *(float4*)(op + 4) = s1;
}

// ---------------- launch --------------------------------------------------
extern "C" void kernel_launch(void* const* d_in, const int* in_sizes, int n_in,
                              void* d_out, int out_size, void* d_ws, size_t ws_size,
                              hipStream_t stream) {
  const float* hs = (const float*)d_in[0];
  const float* am = (const float*)d_in[1];
  const float* Wq = (const float*)d_in[2];
  const float* bq = (const float*)d_in[3];
  const float* Wk = (const float*)d_in[4];
  const float* bk = (const float*)d_in[5];
  const float* Wv = (const float*)d_in[6];
  const float* bv = (const float*)d_in[7];
  float* out = (float*)d_out;

  char* ws = (char*)d_ws;
  _Float16* hsb = (_Float16*)(ws);
  _Float16* wb  = (_Float16*)(ws + 8388608);
  _Float16* Qf  = (_Float16*)(ws + 14680064);
  _Float16* Kf  = (_Float16*)(ws + 23068672);
  _Float16* Vf  = (_Float16*)(ws + 31457280);

  convert_kernel<<<7168, 256, 0, stream>>>(
      (const float4*)hs, (const float4*)Wq, (const float4*)Wk, (const float4*)Wv, hsb, wb);
  qkv_gemm<<<192, 512, 0, stream>>>(hsb, wb, bq, bk, bv, Qf, Kf, Vf);
  attn_kernel<<<2048, 256, 0, stream>>>(Qf, Kf, Vf, am, out);
}